// Round 3
// baseline (3684.503 us; speedup 1.0000x reference)
//
#include <hip/hip_runtime.h>
#include <math.h>

#define BATCH 4
#define NSEQ 8193
#define CDIM 768
#define TOPK 12
#define NCHUNK 32      // 32 chunks x 256 tokens
#define BK 16
#define NDBLK 12       // 768 / 64
#define NCAND 16       // fp32 candidates per (b,d) for fp64 rescoring

// ---------- sorted-descending top-k insertion helpers ----------
__device__ __forceinline__ void ins_f(float v, float (&lst)[TOPK]) {
  if (v > lst[TOPK - 1]) {
#pragma unroll
    for (int r = 0; r < TOPK; ++r) {
      bool g = v > lst[r];
      float disp = g ? lst[r] : v;
      lst[r] = g ? v : lst[r];
      v = disp;
    }
  }
}

template <int DP>
__device__ __forceinline__ void ins_fi(float v, int i, float (&lv)[DP], int (&li)[DP]) {
  if ((v > lv[DP - 1]) || (v == lv[DP - 1] && i < li[DP - 1])) {
#pragma unroll
    for (int r = 0; r < DP; ++r) {
      bool g = (v > lv[r]) || (v == lv[r] && i < li[r]);
      float dv = g ? lv[r] : v;
      int di = g ? li[r] : i;
      lv[r] = g ? v : lv[r];
      li[r] = g ? i : li[r];
      v = dv;
      i = di;
    }
  }
}

__device__ __forceinline__ void ins_di(double v, int i, double (&lv)[TOPK], int (&li)[TOPK]) {
#pragma unroll
  for (int r = 0; r < TOPK; ++r) {
    bool g = (v > lv[r]) || (v == lv[r] && i < li[r]);
    double dv = g ? lv[r] : v;
    int di = g ? li[r] : i;
    lv[r] = g ? v : lv[r];
    li[r] = g ? i : li[r];
    v = dv;
    i = di;
  }
}

// ---------- kernel A: cls-token QKV rows (token 0), fp32 ----------
__global__ void cls_kernel(const float* __restrict__ x, const float* __restrict__ W,
                           const float* __restrict__ bias, float* __restrict__ cls) {
  int idx = blockIdx.x * 256 + threadIdx.x;  // [0, 3*B*C)
  if (idx >= 3 * BATCH * CDIM) return;
  int qty = idx / (BATCH * CDIM);
  int rem = idx % (BATCH * CDIM);
  int b = rem / CDIM;
  int d = rem % CDIM;
  int o = qty * CDIM + d;
  const float* xr = x + (size_t)b * NSEQ * CDIM;  // token 0 row
  const float* wr = W + (size_t)o * CDIM;
  float s0 = 0.f, s1 = 0.f, s2 = 0.f, s3 = 0.f;
  for (int c = 0; c < CDIM; c += 4) {
    s0 = fmaf(xr[c + 0], wr[c + 0], s0);
    s1 = fmaf(xr[c + 1], wr[c + 1], s1);
    s2 = fmaf(xr[c + 2], wr[c + 2], s2);
    s3 = fmaf(xr[c + 3], wr[c + 3], s3);
  }
  float s = (s0 + s1) + (s2 + s3);
  s += bias[o];
  cls[qty * (BATCH * CDIM) + b * CDIM + d] = s;  // cls[3][B][C]
}

// ---------- kernel B: fused fp32 QKV GEMM + m-write + parallel Q/K chunk top-12 ----------
__launch_bounds__(256, 3)
__global__ void fused_kernel(const float* __restrict__ x, const float* __restrict__ W,
                             const float* __restrict__ bias, const float* __restrict__ cls,
                             float* __restrict__ out,
                             float* __restrict__ candQ, float* __restrict__ candK) {
  __shared__ __align__(16) union SM {
    struct { float xs[BK][132]; float w[3][BK][68]; } st;  // staging (transposed tiles)
    float bufq[128][68];                                   // epilogue redistribution
    float part[4][64][13];                                 // partial top-12 lists (padded)
  } sm;

  const int tid = threadIdx.x;
  const int chunk = blockIdx.x;  // 0..31
  const int dblk = blockIdx.y;   // 0..11
  const int b = blockIdx.z;      // 0..3
  const int tg = tid >> 4;       // token group 0..15 (8 tokens each)
  const int dg = tid & 15;       // d group 0..15 (4 d each)
  const int d0 = dblk * 64;
  const int sq = tid >> 6;       // scan quarter 0..3
  const int sd = tid & 63;       // scan d index 0..63

  // persistent per-thread partial top-12 (quarter sq of tokens, d = d0+sd)
  float tqp[TOPK], tkp[TOPK];
#pragma unroll
  for (int r = 0; r < TOPK; ++r) { tqp[r] = -INFINITY; tkp[r] = -INFINITY; }

  // per-thread cls values for its 4 d's (GEMM-role mapping)
  float qc[4], kc[4], iv[4];
#pragma unroll
  for (int j = 0; j < 4; ++j) {
    int d = d0 + dg * 4 + j;
    float q_ = cls[0 * (BATCH * CDIM) + b * CDIM + d];
    float k_ = cls[1 * (BATCH * CDIM) + b * CDIM + d];
    float v_ = cls[2 * (BATCH * CDIM) + b * CDIM + d];
    qc[j] = q_; kc[j] = k_;
    iv[j] = (q_ * k_) * (1.0f + fabsf(v_));
  }

  for (int sub = 0; sub < 2; ++sub) {
    const int n0 = 1 + chunk * 256 + sub * 128;  // global token row (skip cls row 0)
    float accq[8][4], acck[8][4], accv[8][4];
#pragma unroll
    for (int i2 = 0; i2 < 8; ++i2)
#pragma unroll
      for (int j = 0; j < 4; ++j) { accq[i2][j] = 0.f; acck[i2][j] = 0.f; accv[i2][j] = 0.f; }

    for (int k0 = 0; k0 < CDIM; k0 += BK) {
      __syncthreads();
      // stage x tile (128 tokens x 16 k), transposed to xs[k][token]
#pragma unroll
      for (int r = 0; r < 2; ++r) {
        int id = tid + r * 256;
        int tok = id >> 2, kq = id & 3;
        const float4 v4 = *(const float4*)(x + ((size_t)(b * NSEQ + n0 + tok)) * CDIM + k0 + kq * 4);
        sm.st.xs[kq * 4 + 0][tok] = v4.x;
        sm.st.xs[kq * 4 + 1][tok] = v4.y;
        sm.st.xs[kq * 4 + 2][tok] = v4.z;
        sm.st.xs[kq * 4 + 3][tok] = v4.w;
      }
      // stage W tiles (3 x 64 d x 16 k), transposed to w[qty][k][d]
#pragma unroll
      for (int r = 0; r < 3; ++r) {
        int id = tid + r * 256;
        int qty = id >> 8, rem = id & 255;
        int dloc = rem >> 2, kq = rem & 3;
        const float4 v4 = *(const float4*)(W + (size_t)(qty * CDIM + d0 + dloc) * CDIM + k0 + kq * 4);
        sm.st.w[qty][kq * 4 + 0][dloc] = v4.x;
        sm.st.w[qty][kq * 4 + 1][dloc] = v4.y;
        sm.st.w[qty][kq * 4 + 2][dloc] = v4.z;
        sm.st.w[qty][kq * 4 + 3][dloc] = v4.w;
      }
      __syncthreads();
#pragma unroll
      for (int kk = 0; kk < BK; ++kk) {
        float a[8];
        const float4 a0 = *(const float4*)&sm.st.xs[kk][tg * 8];
        const float4 a1 = *(const float4*)&sm.st.xs[kk][tg * 8 + 4];
        a[0] = a0.x; a[1] = a0.y; a[2] = a0.z; a[3] = a0.w;
        a[4] = a1.x; a[5] = a1.y; a[6] = a1.z; a[7] = a1.w;
        const float4 wq4 = *(const float4*)&sm.st.w[0][kk][dg * 4];
        const float4 wk4 = *(const float4*)&sm.st.w[1][kk][dg * 4];
        const float4 wv4 = *(const float4*)&sm.st.w[2][kk][dg * 4];
        const float wqa[4] = {wq4.x, wq4.y, wq4.z, wq4.w};
        const float wka[4] = {wk4.x, wk4.y, wk4.z, wk4.w};
        const float wva[4] = {wv4.x, wv4.y, wv4.z, wv4.w};
#pragma unroll
        for (int i2 = 0; i2 < 8; ++i2) {
          const float av = a[i2];
#pragma unroll
          for (int j = 0; j < 4; ++j) {
            accq[i2][j] = fmaf(av, wqa[j], accq[i2][j]);
            acck[i2][j] = fmaf(av, wka[j], acck[i2][j]);
            accv[i2][j] = fmaf(av, wva[j], accv[i2][j]);
          }
        }
      }
    }

    // bias (loaded here, not held across GEMM)
    float bq[4], bk[4], bv[4];
#pragma unroll
    for (int j = 0; j < 4; ++j) {
      int d = d0 + dg * 4 + j;
      bq[j] = bias[d]; bk[j] = bias[CDIM + d]; bv[j] = bias[2 * CDIM + d];
    }
#pragma unroll
    for (int i2 = 0; i2 < 8; ++i2)
#pragma unroll
      for (int j = 0; j < 4; ++j) {
        accq[i2][j] += bq[j];
        acck[i2][j] += bk[j];
        accv[i2][j] += bv[j];
      }

    // write m = v^2 + 2v + inter_v into d_out rows 1..8192 (fp32)
#pragma unroll
    for (int i2 = 0; i2 < 8; ++i2) {
      float4 mf;
      mf.x = fmaf(accv[i2][0], accv[i2][0] + 2.0f, iv[0]);
      mf.y = fmaf(accv[i2][1], accv[i2][1] + 2.0f, iv[1]);
      mf.z = fmaf(accv[i2][2], accv[i2][2] + 2.0f, iv[2]);
      mf.w = fmaf(accv[i2][3], accv[i2][3] + 2.0f, iv[3]);
      *(float4*)(out + ((size_t)(b * NSEQ + n0 + tg * 8 + i2)) * CDIM + d0 + dg * 4) = mf;
    }

    // ---- pass Q: a_q = q_cls*k + q ; parallel scan (all 256 threads, 32 rows each)
    __syncthreads();  // inner loop done reading st before bufq overwrite
#pragma unroll
    for (int i2 = 0; i2 < 8; ++i2) {
      float4 t4;
      t4.x = fmaf(qc[0], acck[i2][0], accq[i2][0]);
      t4.y = fmaf(qc[1], acck[i2][1], accq[i2][1]);
      t4.z = fmaf(qc[2], acck[i2][2], accq[i2][2]);
      t4.w = fmaf(qc[3], acck[i2][3], accq[i2][3]);
      *(float4*)&sm.bufq[tg * 8 + i2][dg * 4] = t4;
    }
    __syncthreads();
    for (int t = sq * 32; t < sq * 32 + 32; ++t) ins_f(sm.bufq[t][sd], tqp);

    // ---- pass K: a_k = k_cls*q + k
    __syncthreads();
#pragma unroll
    for (int i2 = 0; i2 < 8; ++i2) {
      float4 t4;
      t4.x = fmaf(kc[0], accq[i2][0], acck[i2][0]);
      t4.y = fmaf(kc[1], accq[i2][1], acck[i2][1]);
      t4.z = fmaf(kc[2], accq[i2][2], acck[i2][2]);
      t4.w = fmaf(kc[3], accq[i2][3], acck[i2][3]);
      *(float4*)&sm.bufq[tg * 8 + i2][dg * 4] = t4;
    }
    __syncthreads();
    for (int t = sq * 32; t < sq * 32 + 32; ++t) ins_f(sm.bufq[t][sd], tkp);
    // next sub's k0-loop top barrier protects bufq -> st overwrite
  }  // sub

  // ---- merge Q partials across quarters, write candQ
  __syncthreads();
#pragma unroll
  for (int r = 0; r < TOPK; ++r) sm.part[sq][sd][r] = tqp[r];
  __syncthreads();
  if (tid < 64) {
    for (int qq = 1; qq < 4; ++qq)
#pragma unroll
      for (int r = 0; r < TOPK; ++r) ins_f(sm.part[qq][tid][r], tqp);
    size_t base = ((size_t)(b * CDIM + d0 + tid) * NCHUNK + chunk) * TOPK;
#pragma unroll
    for (int r = 0; r < TOPK; ++r) candQ[base + r] = tqp[r];
  }
  // ---- merge K partials, write candK
  __syncthreads();
#pragma unroll
  for (int r = 0; r < TOPK; ++r) sm.part[sq][sd][r] = tkp[r];
  __syncthreads();
  if (tid < 64) {
    for (int qq = 1; qq < 4; ++qq)
#pragma unroll
      for (int r = 0; r < TOPK; ++r) ins_f(sm.part[qq][tid][r], tkp);
    size_t base = ((size_t)(b * CDIM + d0 + tid) * NCHUNK + chunk) * TOPK;
#pragma unroll
    for (int r = 0; r < TOPK; ++r) candK[base + r] = tkp[r];
  }
}

// ---------- kernel E: fp32 top-16 candidates per (b,d) from the m map in out ----------
__global__ void vscan_kernel(const float* __restrict__ mout,
                             float* __restrict__ cVv, int* __restrict__ cVi) {
  __shared__ float pv[4][64][17];
  __shared__ int pi[4][64][17];
  const int tid = threadIdx.x;
  const int b = blockIdx.y;
  const int dl = tid & 63;
  const int d = blockIdx.x * 64 + dl;
  const int q = tid >> 6;
  float lv[NCAND];
  int li[NCAND];
#pragma unroll
  for (int r = 0; r < NCAND; ++r) { lv[r] = -INFINITY; li[r] = 0x7fffffff; }
  const float* col = mout + ((size_t)b * NSEQ + 1) * CDIM + d;
  const int t0 = q * 2048;
  for (int t = t0; t < t0 + 2048; t += 4) {
    float v0 = col[(size_t)(t + 0) * CDIM];
    float v1 = col[(size_t)(t + 1) * CDIM];
    float v2 = col[(size_t)(t + 2) * CDIM];
    float v3 = col[(size_t)(t + 3) * CDIM];
    ins_fi<NCAND>(v0, t + 0, lv, li);
    ins_fi<NCAND>(v1, t + 1, lv, li);
    ins_fi<NCAND>(v2, t + 2, lv, li);
    ins_fi<NCAND>(v3, t + 3, lv, li);
  }
#pragma unroll
  for (int r = 0; r < NCAND; ++r) { pv[q][dl][r] = lv[r]; pi[q][dl][r] = li[r]; }
  __syncthreads();
  if (tid < 64) {
    for (int qq = 1; qq < 4; ++qq)
#pragma unroll
      for (int r = 0; r < NCAND; ++r) ins_fi<NCAND>(pv[qq][tid][r], pi[qq][tid][r], lv, li);
    size_t base = ((size_t)b * CDIM + d) * NCAND;
#pragma unroll
    for (int r = 0; r < NCAND; ++r) { cVv[base + r] = lv[r]; cVi[base + r] = li[r]; }
  }
}

// ---------- kernel C: merge Q/K chunk candidates -> qm/km rows; cls row 0 ----------
__global__ void merge_qk_kernel(const float* __restrict__ cls,
                                const float* __restrict__ candQ, const float* __restrict__ candK,
                                float* __restrict__ qm, float* __restrict__ km,
                                float* __restrict__ vm) {
  int idx = blockIdx.x * 256 + threadIdx.x;  // [0, B*C)
  int b = idx / CDIM, d = idx % CDIM;
  float tq[TOPK], tk[TOPK];
#pragma unroll
  for (int r = 0; r < TOPK; ++r) { tq[r] = -INFINITY; tk[r] = -INFINITY; }
  size_t base = (size_t)(b * CDIM + d) * NCHUNK * TOPK;
  for (int c = 0; c < NCHUNK * TOPK; ++c) {
    ins_f(candQ[base + c], tq);
    ins_f(candK[base + c], tk);
  }
  qm[(size_t)(b * 13 + 0) * CDIM + d] = cls[0 * (BATCH * CDIM) + b * CDIM + d];
  km[(size_t)(b * 13 + 0) * CDIM + d] = cls[1 * (BATCH * CDIM) + b * CDIM + d];
  vm[(size_t)(b * 13 + 0) * CDIM + d] = cls[2 * (BATCH * CDIM) + b * CDIM + d];
#pragma unroll
  for (int r = 0; r < TOPK; ++r) {
    qm[(size_t)(b * 13 + 1 + r) * CDIM + d] = tq[r];
    km[(size_t)(b * 13 + 1 + r) * CDIM + d] = tk[r];
  }
}

// ---------- kernel F: fp64 rescoring of the 16 V candidates -> exact top-12 ----------
__global__ void rescore_kernel(const float* __restrict__ x, const float* __restrict__ W,
                               const float* __restrict__ bias, const float* __restrict__ cls,
                               const int* __restrict__ cVi,
                               float* __restrict__ vm, int* __restrict__ vidx) {
  const int d = blockIdx.x;
  const int b = blockIdx.y;
  const int tid = threadIdx.x;
  __shared__ int sidx[NCAND];
  __shared__ double spart[NCAND][17];
  if (tid < NCAND) sidx[tid] = cVi[((size_t)b * CDIM + d) * NCAND + tid];
  __syncthreads();
  const int c = tid >> 4, e = tid & 15;
  const float* xr = x + ((size_t)b * NSEQ + 1 + sidx[c]) * CDIM + e * 48;
  const float* wr = W + (size_t)(2 * CDIM + d) * CDIM + e * 48;
  double s = 0.0;
#pragma unroll 4
  for (int j = 0; j < 48; ++j) s = fma((double)xr[j], (double)wr[j], s);
  spart[c][e] = s;
  __syncthreads();
  if (tid < NCAND) {
    double v = 0.0;
    for (int ee = 0; ee < 16; ++ee) v += spart[tid][ee];  // fixed deterministic order
    v += (double)bias[2 * CDIM + d];
    double qc = (double)cls[0 * (BATCH * CDIM) + b * CDIM + d];
    double kc = (double)cls[1 * (BATCH * CDIM) + b * CDIM + d];
    double vc = (double)cls[2 * (BATCH * CDIM) + b * CDIM + d];
    double ivd = (qc * kc) * (1.0 + fabs(vc));
    spart[tid][16] = fma(v, v + 2.0, ivd);
  }
  __syncthreads();
  if (tid == 0) {
    double lv[TOPK];
    int li[TOPK];
#pragma unroll
    for (int r = 0; r < TOPK; ++r) { lv[r] = -INFINITY; li[r] = 0x7fffffff; }
    for (int cc = 0; cc < NCAND; ++cc) ins_di(spart[cc][16], sidx[cc], lv, li);
#pragma unroll
    for (int r = 0; r < TOPK; ++r) {
      vm[(size_t)(b * 13 + 1 + r) * CDIM + d] = (float)lv[r];
      vidx[(size_t)(b * TOPK + r) * CDIM + d] = li[r];
    }
  }
}

// ---------- kernel D: 13x13 attention + scatter-add ----------
__global__ void attn_kernel(const float* __restrict__ qm, const float* __restrict__ km,
                            const float* __restrict__ vm, const int* __restrict__ vidx,
                            float* __restrict__ out) {
  const int b = blockIdx.x, tid = threadIdx.x;
  __shared__ float att[13][16];
  if (tid < 169) {
    int i = tid / 13, j = tid % 13;
    const float* qr = qm + (size_t)(b * 13 + i) * CDIM;
    const float* kr = km + (size_t)(b * 13 + j) * CDIM;
    float s0 = 0.f, s1 = 0.f, s2 = 0.f, s3 = 0.f;
    for (int c = 0; c < CDIM; c += 4) {
      s0 = fmaf(qr[c + 0], kr[c + 0], s0);
      s1 = fmaf(qr[c + 1], kr[c + 1], s1);
      s2 = fmaf(qr[c + 2], kr[c + 2], s2);
      s3 = fmaf(qr[c + 3], kr[c + 3], s3);
    }
    att[i][j] = ((s0 + s1) + (s2 + s3)) * 0.03608439182435161f;  // 768^-0.5
  }
  __syncthreads();
  if (tid < 13) {
    float mx = -INFINITY;
    float e[13];
#pragma unroll
    for (int j = 0; j < 13; ++j) mx = fmaxf(mx, att[tid][j]);
    float sum = 0.f;
#pragma unroll
    for (int j = 0; j < 13; ++j) { e[j] = expf(att[tid][j] - mx); sum += e[j]; }
    float inv = 1.f / sum;
#pragma unroll
    for (int j = 0; j < 13; ++j) att[tid][j] = e[j] * inv;
  }
  __syncthreads();
  for (int i = tid; i < 13 * CDIM; i += 256) {
    int j = i / CDIM, d = i % CDIM;
    float s = 0.f;
#pragma unroll
    for (int kk = 0; kk < 13; ++kk) s = fmaf(att[j][kk], vm[(size_t)(b * 13 + kk) * CDIM + d], s);
    if (j == 0) {
      out[(size_t)b * NSEQ * CDIM + d] = s;  // cls output row
    } else {
      int t = vidx[(size_t)(b * TOPK + (j - 1)) * CDIM + d];
      size_t o = ((size_t)b * NSEQ + 1 + t) * CDIM + d;
      out[o] += s;  // unique (row,d) targets: no collisions
    }
  }
}

extern "C" void kernel_launch(void* const* d_in, const int* in_sizes, int n_in,
                              void* d_out, int out_size, void* d_ws, size_t ws_size,
                              hipStream_t stream) {
  const float* x = (const float*)d_in[0];
  const float* W = (const float*)d_in[1];
  const float* bias = (const float*)d_in[2];
  float* out = (float*)d_out;
  char* ws = (char*)d_ws;

  float* cls = (float*)(ws + 0);               // 36864 B
  float* qm = (float*)(ws + 36864);            // 159744 B
  float* km = (float*)(ws + 196608);           // 159744 B
  float* vm = (float*)(ws + 356352);           // 159744 B
  int* vidx = (int*)(ws + 516096);             // 147456 B
  float* candQ = (float*)(ws + 663552);        // 4718592 B
  float* candK = (float*)(ws + 5382144);       // 4718592 B
  float* cVv = (float*)(ws + 10100736);        // 196608 B
  int* cVi = (int*)(ws + 10297344);            // 196608 B -> total 10493952 B

  hipLaunchKernelGGL(cls_kernel, dim3(36), dim3(256), 0, stream, x, W, bias, cls);
  hipLaunchKernelGGL(fused_kernel, dim3(NCHUNK, NDBLK, BATCH), dim3(256), 0, stream,
                     x, W, bias, cls, out, candQ, candK);
  hipLaunchKernelGGL(vscan_kernel, dim3(NDBLK, BATCH), dim3(256), 0, stream, out, cVv, cVi);
  hipLaunchKernelGGL(merge_qk_kernel, dim3(12), dim3(256), 0, stream, cls, candQ, candK, qm, km, vm);
  hipLaunchKernelGGL(rescore_kernel, dim3(CDIM, BATCH), dim3(256), 0, stream,
                     x, W, bias, cls, cVi, vm, vidx);
  hipLaunchKernelGGL(attn_kernel, dim3(BATCH), dim3(256), 0, stream, qm, km, vm, vidx, out);
}

// Round 4
// 2145.602 us; speedup vs baseline: 1.7172x; 1.7172x over previous
//
#include <hip/hip_runtime.h>
#include <math.h>

#define BATCH 4
#define NSEQ 8193
#define CDIM 768
#define TOPK 12
#define NCHUNK 32      // 32 chunks x 256 tokens
#define BK 16
#define NDBLK 12       // 768 / 64
#define NCAND 16       // fp32 V candidates per chunk and per (b,d), fp64-rescored

// ---------- sorted-descending top-k insertion helpers ----------
__device__ __forceinline__ void ins_f(float v, float (&lst)[TOPK]) {
  if (v > lst[TOPK - 1]) {
#pragma unroll
    for (int r = 0; r < TOPK; ++r) {
      bool g = v > lst[r];
      float disp = g ? lst[r] : v;
      lst[r] = g ? v : lst[r];
      v = disp;
    }
  }
}

template <int DP>
__device__ __forceinline__ void ins_fi(float v, int i, float (&lv)[DP], int (&li)[DP]) {
  if ((v > lv[DP - 1]) || (v == lv[DP - 1] && i < li[DP - 1])) {
#pragma unroll
    for (int r = 0; r < DP; ++r) {
      bool g = (v > lv[r]) || (v == lv[r] && i < li[r]);
      float dv = g ? lv[r] : v;
      int di = g ? li[r] : i;
      lv[r] = g ? v : lv[r];
      li[r] = g ? i : li[r];
      v = dv;
      i = di;
    }
  }
}

__device__ __forceinline__ void ins_di(double v, int i, double (&lv)[TOPK], int (&li)[TOPK]) {
#pragma unroll
  for (int r = 0; r < TOPK; ++r) {
    bool g = (v > lv[r]) || (v == lv[r] && i < li[r]);
    double dv = g ? lv[r] : v;
    int di = g ? li[r] : i;
    lv[r] = g ? v : lv[r];
    li[r] = g ? i : li[r];
    v = dv;
    i = di;
  }
}

// ---------- kernel A: cls-token QKV rows (token 0), fp32 ----------
__global__ void cls_kernel(const float* __restrict__ x, const float* __restrict__ W,
                           const float* __restrict__ bias, float* __restrict__ cls) {
  int idx = blockIdx.x * 256 + threadIdx.x;  // [0, 3*B*C)
  if (idx >= 3 * BATCH * CDIM) return;
  int qty = idx / (BATCH * CDIM);
  int rem = idx % (BATCH * CDIM);
  int b = rem / CDIM;
  int d = rem % CDIM;
  int o = qty * CDIM + d;
  const float* xr = x + (size_t)b * NSEQ * CDIM;  // token 0 row
  const float* wr = W + (size_t)o * CDIM;
  float s0 = 0.f, s1 = 0.f, s2 = 0.f, s3 = 0.f;
  for (int c = 0; c < CDIM; c += 4) {
    s0 = fmaf(xr[c + 0], wr[c + 0], s0);
    s1 = fmaf(xr[c + 1], wr[c + 1], s1);
    s2 = fmaf(xr[c + 2], wr[c + 2], s2);
    s3 = fmaf(xr[c + 3], wr[c + 3], s3);
  }
  float s = (s0 + s1) + (s2 + s3);
  s += bias[o];
  cls[qty * (BATCH * CDIM) + b * CDIM + d] = s;  // cls[3][B][C]
}

// ---------- kernel B: fused fp32 QKV GEMM + m-write + parallel Q/K/V chunk top-k ----------
__launch_bounds__(256, 2)
__global__ void fused_kernel(const float* __restrict__ x, const float* __restrict__ W,
                             const float* __restrict__ bias, const float* __restrict__ cls,
                             float* __restrict__ out,
                             float* __restrict__ candQ, float* __restrict__ candK,
                             float* __restrict__ candVv, int* __restrict__ candVi) {
  __shared__ __align__(16) union SM {
    struct { float xs[BK][132]; float w[3][BK][68]; } st;   // staging (transposed tiles)
    float bufq[128][68];                                    // epilogue redistribution
    float part[4][64][13];                                  // Q/K partial top-12 lists
    struct { float pv[4][64][17]; int pi[4][64][17]; } pV;  // V partial top-16 lists
  } sm;

  const int tid = threadIdx.x;
  const int chunk = blockIdx.x;  // 0..31
  const int dblk = blockIdx.y;   // 0..11
  const int b = blockIdx.z;      // 0..3
  const int tg = tid >> 4;       // token group 0..15 (8 tokens each)
  const int dg = tid & 15;       // d group 0..15 (4 d each)
  const int d0 = dblk * 64;
  const int sq = tid >> 6;       // scan quarter 0..3
  const int sd = tid & 63;       // scan d index 0..63

  // persistent per-thread partial top-k (quarter sq of tokens, d = d0+sd)
  float tqp[TOPK], tkp[TOPK];
  float tvp[NCAND];
  int tip[NCAND];
#pragma unroll
  for (int r = 0; r < TOPK; ++r) { tqp[r] = -INFINITY; tkp[r] = -INFINITY; }
#pragma unroll
  for (int r = 0; r < NCAND; ++r) { tvp[r] = -INFINITY; tip[r] = 0x7fffffff; }

  // per-thread cls values for its 4 d's (GEMM-role mapping)
  float qc[4], kc[4], iv[4];
#pragma unroll
  for (int j = 0; j < 4; ++j) {
    int d = d0 + dg * 4 + j;
    float q_ = cls[0 * (BATCH * CDIM) + b * CDIM + d];
    float k_ = cls[1 * (BATCH * CDIM) + b * CDIM + d];
    float v_ = cls[2 * (BATCH * CDIM) + b * CDIM + d];
    qc[j] = q_; kc[j] = k_;
    iv[j] = (q_ * k_) * (1.0f + fabsf(v_));
  }

  for (int sub = 0; sub < 2; ++sub) {
    const int n0 = 1 + chunk * 256 + sub * 128;  // global token row (skip cls row 0)
    float accq[8][4], acck[8][4], accv[8][4];
#pragma unroll
    for (int i2 = 0; i2 < 8; ++i2)
#pragma unroll
      for (int j = 0; j < 4; ++j) { accq[i2][j] = 0.f; acck[i2][j] = 0.f; accv[i2][j] = 0.f; }

    for (int k0 = 0; k0 < CDIM; k0 += BK) {
      __syncthreads();
      // stage x tile (128 tokens x 16 k), transposed to xs[k][token]
#pragma unroll
      for (int r = 0; r < 2; ++r) {
        int id = tid + r * 256;
        int tok = id >> 2, kq = id & 3;
        const float4 v4 = *(const float4*)(x + ((size_t)(b * NSEQ + n0 + tok)) * CDIM + k0 + kq * 4);
        sm.st.xs[kq * 4 + 0][tok] = v4.x;
        sm.st.xs[kq * 4 + 1][tok] = v4.y;
        sm.st.xs[kq * 4 + 2][tok] = v4.z;
        sm.st.xs[kq * 4 + 3][tok] = v4.w;
      }
      // stage W tiles (3 x 64 d x 16 k), transposed to w[qty][k][d]
#pragma unroll
      for (int r = 0; r < 3; ++r) {
        int id = tid + r * 256;
        int qty = id >> 8, rem = id & 255;
        int dloc = rem >> 2, kq = rem & 3;
        const float4 v4 = *(const float4*)(W + (size_t)(qty * CDIM + d0 + dloc) * CDIM + k0 + kq * 4);
        sm.st.w[qty][kq * 4 + 0][dloc] = v4.x;
        sm.st.w[qty][kq * 4 + 1][dloc] = v4.y;
        sm.st.w[qty][kq * 4 + 2][dloc] = v4.z;
        sm.st.w[qty][kq * 4 + 3][dloc] = v4.w;
      }
      __syncthreads();
#pragma unroll
      for (int kk = 0; kk < BK; ++kk) {
        float a[8];
        const float4 a0 = *(const float4*)&sm.st.xs[kk][tg * 8];
        const float4 a1 = *(const float4*)&sm.st.xs[kk][tg * 8 + 4];
        a[0] = a0.x; a[1] = a0.y; a[2] = a0.z; a[3] = a0.w;
        a[4] = a1.x; a[5] = a1.y; a[6] = a1.z; a[7] = a1.w;
        const float4 wq4 = *(const float4*)&sm.st.w[0][kk][dg * 4];
        const float4 wk4 = *(const float4*)&sm.st.w[1][kk][dg * 4];
        const float4 wv4 = *(const float4*)&sm.st.w[2][kk][dg * 4];
        const float wqa[4] = {wq4.x, wq4.y, wq4.z, wq4.w};
        const float wka[4] = {wk4.x, wk4.y, wk4.z, wk4.w};
        const float wva[4] = {wv4.x, wv4.y, wv4.z, wv4.w};
#pragma unroll
        for (int i2 = 0; i2 < 8; ++i2) {
          const float av = a[i2];
#pragma unroll
          for (int j = 0; j < 4; ++j) {
            accq[i2][j] = fmaf(av, wqa[j], accq[i2][j]);
            acck[i2][j] = fmaf(av, wka[j], acck[i2][j]);
            accv[i2][j] = fmaf(av, wva[j], accv[i2][j]);
          }
        }
      }
    }

    // bias
    float bq[4], bk[4], bv[4];
#pragma unroll
    for (int j = 0; j < 4; ++j) {
      int d = d0 + dg * 4 + j;
      bq[j] = bias[d]; bk[j] = bias[CDIM + d]; bv[j] = bias[2 * CDIM + d];
    }
#pragma unroll
    for (int i2 = 0; i2 < 8; ++i2)
#pragma unroll
      for (int j = 0; j < 4; ++j) {
        accq[i2][j] += bq[j];
        acck[i2][j] += bk[j];
        accv[i2][j] += bv[j];
      }

    // write m = v^2 + 2v + inter_v into d_out rows 1..8192 (fp32)
#pragma unroll
    for (int i2 = 0; i2 < 8; ++i2) {
      float4 mf;
      mf.x = fmaf(accv[i2][0], accv[i2][0] + 2.0f, iv[0]);
      mf.y = fmaf(accv[i2][1], accv[i2][1] + 2.0f, iv[1]);
      mf.z = fmaf(accv[i2][2], accv[i2][2] + 2.0f, iv[2]);
      mf.w = fmaf(accv[i2][3], accv[i2][3] + 2.0f, iv[3]);
      *(float4*)(out + ((size_t)(b * NSEQ + n0 + tg * 8 + i2)) * CDIM + d0 + dg * 4) = mf;
    }

    // ---- pass Q: a_q = q_cls*k + q ; parallel scan (all 256 threads, 32 rows each)
    __syncthreads();
#pragma unroll
    for (int i2 = 0; i2 < 8; ++i2) {
      float4 t4;
      t4.x = fmaf(qc[0], acck[i2][0], accq[i2][0]);
      t4.y = fmaf(qc[1], acck[i2][1], accq[i2][1]);
      t4.z = fmaf(qc[2], acck[i2][2], accq[i2][2]);
      t4.w = fmaf(qc[3], acck[i2][3], accq[i2][3]);
      *(float4*)&sm.bufq[tg * 8 + i2][dg * 4] = t4;
    }
    __syncthreads();
    for (int t = sq * 32; t < sq * 32 + 32; ++t) ins_f(sm.bufq[t][sd], tqp);

    // ---- pass K: a_k = k_cls*q + k
    __syncthreads();
#pragma unroll
    for (int i2 = 0; i2 < 8; ++i2) {
      float4 t4;
      t4.x = fmaf(kc[0], accq[i2][0], acck[i2][0]);
      t4.y = fmaf(kc[1], accq[i2][1], acck[i2][1]);
      t4.z = fmaf(kc[2], accq[i2][2], acck[i2][2]);
      t4.w = fmaf(kc[3], accq[i2][3], acck[i2][3]);
      *(float4*)&sm.bufq[tg * 8 + i2][dg * 4] = t4;
    }
    __syncthreads();
    for (int t = sq * 32; t < sq * 32 + 32; ++t) ins_f(sm.bufq[t][sd], tkp);

    // ---- pass V: m (fp32, recomputed from accv) with global token index
    __syncthreads();
#pragma unroll
    for (int i2 = 0; i2 < 8; ++i2) {
      float4 t4;
      t4.x = fmaf(accv[i2][0], accv[i2][0] + 2.0f, iv[0]);
      t4.y = fmaf(accv[i2][1], accv[i2][1] + 2.0f, iv[1]);
      t4.z = fmaf(accv[i2][2], accv[i2][2] + 2.0f, iv[2]);
      t4.w = fmaf(accv[i2][3], accv[i2][3] + 2.0f, iv[3]);
      *(float4*)&sm.bufq[tg * 8 + i2][dg * 4] = t4;
    }
    __syncthreads();
    {
      const int gbase = chunk * 256 + sub * 128;
      for (int t = sq * 32; t < sq * 32 + 32; ++t)
        ins_fi<NCAND>(sm.bufq[t][sd], gbase + t, tvp, tip);
    }
    // next sub's k0-loop top barrier protects bufq -> st overwrite
  }  // sub

  // ---- merge Q partials across quarters, write candQ
  __syncthreads();
#pragma unroll
  for (int r = 0; r < TOPK; ++r) sm.part[sq][sd][r] = tqp[r];
  __syncthreads();
  if (tid < 64) {
    for (int qq = 1; qq < 4; ++qq)
#pragma unroll
      for (int r = 0; r < TOPK; ++r) ins_f(sm.part[qq][tid][r], tqp);
    size_t base = ((size_t)(b * CDIM + d0 + tid) * NCHUNK + chunk) * TOPK;
#pragma unroll
    for (int r = 0; r < TOPK; ++r) candQ[base + r] = tqp[r];
  }
  // ---- merge K partials, write candK
  __syncthreads();
#pragma unroll
  for (int r = 0; r < TOPK; ++r) sm.part[sq][sd][r] = tkp[r];
  __syncthreads();
  if (tid < 64) {
    for (int qq = 1; qq < 4; ++qq)
#pragma unroll
      for (int r = 0; r < TOPK; ++r) ins_f(sm.part[qq][tid][r], tkp);
    size_t base = ((size_t)(b * CDIM + d0 + tid) * NCHUNK + chunk) * TOPK;
#pragma unroll
    for (int r = 0; r < TOPK; ++r) candK[base + r] = tkp[r];
  }
  // ---- merge V partials, write candVv/candVi (per-chunk fp32 top-16 + indices)
  __syncthreads();
#pragma unroll
  for (int r = 0; r < NCAND; ++r) { sm.pV.pv[sq][sd][r] = tvp[r]; sm.pV.pi[sq][sd][r] = tip[r]; }
  __syncthreads();
  if (tid < 64) {
    for (int qq = 1; qq < 4; ++qq)
#pragma unroll
      for (int r = 0; r < NCAND; ++r) ins_fi<NCAND>(sm.pV.pv[qq][tid][r], sm.pV.pi[qq][tid][r], tvp, tip);
    size_t base = ((size_t)(b * CDIM + d0 + tid) * NCHUNK + chunk) * NCAND;
#pragma unroll
    for (int r = 0; r < NCAND; ++r) { candVv[base + r] = tvp[r]; candVi[base + r] = tip[r]; }
  }
}

// ---------- kernel E: merge V chunk candidates -> global fp32 top-16 indices per (b,d) ----------
__global__ void vmerge_kernel(const float* __restrict__ candVv, const int* __restrict__ candVi,
                              int* __restrict__ cVi) {
  __shared__ float pv[4][64][17];
  __shared__ int pi[4][64][17];
  const int tid = threadIdx.x;
  const int pr = blockIdx.x * 64 + (tid & 63);  // (b,d) pair index
  const int q = tid >> 6;
  float lv[NCAND];
  int li[NCAND];
#pragma unroll
  for (int r = 0; r < NCAND; ++r) { lv[r] = -INFINITY; li[r] = 0x7fffffff; }
  size_t base = ((size_t)pr * NCHUNK + q * 8) * NCAND;
  for (int c = 0; c < 8 * NCAND; ++c) ins_fi<NCAND>(candVv[base + c], candVi[base + c], lv, li);
#pragma unroll
  for (int r = 0; r < NCAND; ++r) { pv[q][tid & 63][r] = lv[r]; pi[q][tid & 63][r] = li[r]; }
  __syncthreads();
  if (tid < 64) {
    for (int qq = 1; qq < 4; ++qq)
#pragma unroll
      for (int r = 0; r < NCAND; ++r) ins_fi<NCAND>(pv[qq][tid][r], pi[qq][tid][r], lv, li);
    size_t ob = (size_t)(blockIdx.x * 64 + tid) * NCAND;
#pragma unroll
    for (int r = 0; r < NCAND; ++r) cVi[ob + r] = li[r];
  }
}

// ---------- kernel C: merge Q/K chunk candidates -> qm/km rows; cls row 0 ----------
__global__ void merge_qk_kernel(const float* __restrict__ cls,
                                const float* __restrict__ candQ, const float* __restrict__ candK,
                                float* __restrict__ qm, float* __restrict__ km,
                                float* __restrict__ vm) {
  __shared__ float pq[4][64][13];
  __shared__ float pk[4][64][13];
  const int tid = threadIdx.x;
  const int pr = blockIdx.x * 64 + (tid & 63);  // (b,d) pair index
  const int q = tid >> 6;
  float tq[TOPK], tk[TOPK];
#pragma unroll
  for (int r = 0; r < TOPK; ++r) { tq[r] = -INFINITY; tk[r] = -INFINITY; }
  size_t base = ((size_t)pr * NCHUNK + q * 8) * TOPK;
  for (int c = 0; c < 8 * TOPK; ++c) {
    ins_f(candQ[base + c], tq);
    ins_f(candK[base + c], tk);
  }
#pragma unroll
  for (int r = 0; r < TOPK; ++r) { pq[q][tid & 63][r] = tq[r]; pk[q][tid & 63][r] = tk[r]; }
  __syncthreads();
  if (tid < 64) {
    for (int qq = 1; qq < 4; ++qq)
#pragma unroll
      for (int r = 0; r < TOPK; ++r) { ins_f(pq[qq][tid][r], tq); ins_f(pk[qq][tid][r], tk); }
    int pr2 = blockIdx.x * 64 + tid;
    int b = pr2 / CDIM, d = pr2 % CDIM;
    qm[(size_t)(b * 13 + 0) * CDIM + d] = cls[0 * (BATCH * CDIM) + b * CDIM + d];
    km[(size_t)(b * 13 + 0) * CDIM + d] = cls[1 * (BATCH * CDIM) + b * CDIM + d];
    vm[(size_t)(b * 13 + 0) * CDIM + d] = cls[2 * (BATCH * CDIM) + b * CDIM + d];
#pragma unroll
    for (int r = 0; r < TOPK; ++r) {
      qm[(size_t)(b * 13 + 1 + r) * CDIM + d] = tq[r];
      km[(size_t)(b * 13 + 1 + r) * CDIM + d] = tk[r];
    }
  }
}

// ---------- kernel F: fp64 rescoring of the 16 V candidates -> exact top-12 ----------
__global__ void rescore_kernel(const float* __restrict__ x, const float* __restrict__ W,
                               const float* __restrict__ bias, const float* __restrict__ cls,
                               const int* __restrict__ cVi,
                               float* __restrict__ vm, int* __restrict__ vidx) {
  const int d = blockIdx.x;
  const int b = blockIdx.y;
  const int tid = threadIdx.x;
  __shared__ int sidx[NCAND];
  __shared__ double spart[NCAND][17];
  if (tid < NCAND) sidx[tid] = cVi[((size_t)b * CDIM + d) * NCAND + tid];
  __syncthreads();
  const int c = tid >> 4, e = tid & 15;
  const float* xr = x + ((size_t)b * NSEQ + 1 + sidx[c]) * CDIM + e * 48;
  const float* wr = W + (size_t)(2 * CDIM + d) * CDIM + e * 48;
  double s = 0.0;
#pragma unroll 4
  for (int j = 0; j < 48; ++j) s = fma((double)xr[j], (double)wr[j], s);
  spart[c][e] = s;
  __syncthreads();
  if (tid < NCAND) {
    double v = 0.0;
    for (int ee = 0; ee < 16; ++ee) v += spart[tid][ee];  // fixed deterministic order
    v += (double)bias[2 * CDIM + d];
    double qc = (double)cls[0 * (BATCH * CDIM) + b * CDIM + d];
    double kc = (double)cls[1 * (BATCH * CDIM) + b * CDIM + d];
    double vc = (double)cls[2 * (BATCH * CDIM) + b * CDIM + d];
    double ivd = (qc * kc) * (1.0 + fabs(vc));
    spart[tid][16] = fma(v, v + 2.0, ivd);
  }
  __syncthreads();
  if (tid == 0) {
    double lv[TOPK];
    int li[TOPK];
#pragma unroll
    for (int r = 0; r < TOPK; ++r) { lv[r] = -INFINITY; li[r] = 0x7fffffff; }
    for (int cc = 0; cc < NCAND; ++cc) ins_di(spart[cc][16], sidx[cc], lv, li);
#pragma unroll
    for (int r = 0; r < TOPK; ++r) {
      vm[(size_t)(b * 13 + 1 + r) * CDIM + d] = (float)lv[r];
      vidx[(size_t)(b * TOPK + r) * CDIM + d] = li[r];
    }
  }
}

// ---------- kernel D: 13x13 attention + scatter-add ----------
__global__ void attn_kernel(const float* __restrict__ qm, const float* __restrict__ km,
                            const float* __restrict__ vm, const int* __restrict__ vidx,
                            float* __restrict__ out) {
  const int b = blockIdx.x, tid = threadIdx.x;
  __shared__ float att[13][16];
  if (tid < 169) {
    int i = tid / 13, j = tid % 13;
    const float* qr = qm + (size_t)(b * 13 + i) * CDIM;
    const float* kr = km + (size_t)(b * 13 + j) * CDIM;
    float s0 = 0.f, s1 = 0.f, s2 = 0.f, s3 = 0.f;
    for (int c = 0; c < CDIM; c += 4) {
      s0 = fmaf(qr[c + 0], kr[c + 0], s0);
      s1 = fmaf(qr[c + 1], kr[c + 1], s1);
      s2 = fmaf(qr[c + 2], kr[c + 2], s2);
      s3 = fmaf(qr[c + 3], kr[c + 3], s3);
    }
    att[i][j] = ((s0 + s1) + (s2 + s3)) * 0.03608439182435161f;  // 768^-0.5
  }
  __syncthreads();
  if (tid < 13) {
    float mx = -INFINITY;
    float e[13];
#pragma unroll
    for (int j = 0; j < 13; ++j) mx = fmaxf(mx, att[tid][j]);
    float sum = 0.f;
#pragma unroll
    for (int j = 0; j < 13; ++j) { e[j] = expf(att[tid][j] - mx); sum += e[j]; }
    float inv = 1.f / sum;
#pragma unroll
    for (int j = 0; j < 13; ++j) att[tid][j] = e[j] * inv;
  }
  __syncthreads();
  for (int i = tid; i < 13 * CDIM; i += 256) {
    int j = i / CDIM, d = i % CDIM;
    float s = 0.f;
#pragma unroll
    for (int kk = 0; kk < 13; ++kk) s = fmaf(att[j][kk], vm[(size_t)(b * 13 + kk) * CDIM + d], s);
    if (j == 0) {
      out[(size_t)b * NSEQ * CDIM + d] = s;  // cls output row
    } else {
      int t = vidx[(size_t)(b * TOPK + (j - 1)) * CDIM + d];
      size_t o = ((size_t)b * NSEQ + 1 + t) * CDIM + d;
      out[o] += s;  // unique (row,d) targets: no collisions
    }
  }
}

extern "C" void kernel_launch(void* const* d_in, const int* in_sizes, int n_in,
                              void* d_out, int out_size, void* d_ws, size_t ws_size,
                              hipStream_t stream) {
  const float* x = (const float*)d_in[0];
  const float* W = (const float*)d_in[1];
  const float* bias = (const float*)d_in[2];
  float* out = (float*)d_out;
  char* ws = (char*)d_ws;

  float* cls = (float*)(ws + 0);               // 36864 B
  float* qm = (float*)(ws + 36864);            // 159744 B
  float* km = (float*)(ws + 196608);           // 159744 B
  float* vm = (float*)(ws + 356352);           // 159744 B
  int* vidx = (int*)(ws + 516096);             // 147456 B
  float* candQ = (float*)(ws + 663552);        // 4718592 B
  float* candK = (float*)(ws + 5382144);       // 4718592 B
  float* candVv = (float*)(ws + 10100736);     // 6291456 B
  int* candVi = (int*)(ws + 16392192);         // 6291456 B
  int* cVi = (int*)(ws + 22683648);            // 196608 B -> total 22880256 B

  hipLaunchKernelGGL(cls_kernel, dim3(36), dim3(256), 0, stream, x, W, bias, cls);
  hipLaunchKernelGGL(fused_kernel, dim3(NCHUNK, NDBLK, BATCH), dim3(256), 0, stream,
                     x, W, bias, cls, out, candQ, candK, candVv, candVi);
  hipLaunchKernelGGL(vmerge_kernel, dim3(BATCH * CDIM / 64), dim3(256), 0, stream,
                     candVv, candVi, cVi);
  hipLaunchKernelGGL(merge_qk_kernel, dim3(BATCH * CDIM / 64), dim3(256), 0, stream,
                     cls, candQ, candK, qm, km, vm);
  hipLaunchKernelGGL(rescore_kernel, dim3(CDIM, BATCH), dim3(256), 0, stream,
                     x, W, bias, cls, cVi, vm, vidx);
  hipLaunchKernelGGL(attn_kernel, dim3(BATCH), dim3(256), 0, stream, qm, km, vm, vidx, out);
}

// Round 5
// 772.441 us; speedup vs baseline: 4.7699x; 2.7777x over previous
//
#include <hip/hip_runtime.h>
#include <math.h>

#define BATCH 4
#define NSEQ 8193
#define CDIM 768
#define TOPK 12
#define NCHUNK 32      // 32 chunks x 256 tokens (2 subs of 128)
#define NSUB 64        // 64 subchunks x 128 tokens (V candidates granularity)
#define PCV 12         // per-subchunk V candidates (packed u32)
#define NCAND 32       // global V candidates, fp64-rescored
#define NDBLK 12       // 768 / 64

typedef __attribute__((ext_vector_type(8))) __bf16 bf16x8;
typedef __attribute__((ext_vector_type(4))) __bf16 bf16x4;
typedef __attribute__((ext_vector_type(4))) float f32x4;

// ---------- top-k insertion helpers ----------
__device__ __forceinline__ void ins_f(float v, float (&lst)[TOPK]) {
  if (v > lst[TOPK - 1]) {
#pragma unroll
    for (int r = 0; r < TOPK; ++r) {
      bool g = v > lst[r];
      float disp = g ? lst[r] : v;
      lst[r] = g ? v : lst[r];
      v = disp;
    }
  }
}

template <int DP>
__device__ __forceinline__ void ins_u(unsigned v, unsigned (&lst)[DP]) {
  if (v > lst[DP - 1]) {
#pragma unroll
    for (int r = 0; r < DP; ++r) {
      bool g = v > lst[r];
      unsigned dv = g ? lst[r] : v;
      lst[r] = g ? v : lst[r];
      v = dv;
    }
  }
}

__device__ __forceinline__ void ins_di(double v, int i, double (&lv)[TOPK], int (&li)[TOPK]) {
#pragma unroll
  for (int r = 0; r < TOPK; ++r) {
    bool g = (v > lv[r]) || (v == lv[r] && i < li[r]);
    double dv = g ? lv[r] : v;
    int di = g ? li[r] : i;
    lv[r] = g ? v : lv[r];
    li[r] = g ? i : li[r];
    v = dv;
    i = di;
  }
}

// value-ordered sortable key with embedded token index (13 bits)
__device__ __forceinline__ unsigned sortkey(float f, int idx) {
  unsigned u = __float_as_uint(f);
  u = (u & 0x80000000u) ? ~u : (u | 0x80000000u);
  return (u & 0xFFFFE000u) | (unsigned)idx;
}

// ---------- kernel A: cls-token QKV rows (token 0), fp32 ----------
__global__ void cls_kernel(const float* __restrict__ x, const float* __restrict__ W,
                           const float* __restrict__ bias, float* __restrict__ cls) {
  int idx = blockIdx.x * 256 + threadIdx.x;
  if (idx >= 3 * BATCH * CDIM) return;
  int qty = idx / (BATCH * CDIM);
  int rem = idx % (BATCH * CDIM);
  int b = rem / CDIM;
  int d = rem % CDIM;
  int o = qty * CDIM + d;
  const float* xr = x + (size_t)b * NSEQ * CDIM;
  const float* wr = W + (size_t)o * CDIM;
  float s0 = 0.f, s1 = 0.f, s2 = 0.f, s3 = 0.f;
  for (int c = 0; c < CDIM; c += 4) {
    s0 = fmaf(xr[c + 0], wr[c + 0], s0);
    s1 = fmaf(xr[c + 1], wr[c + 1], s1);
    s2 = fmaf(xr[c + 2], wr[c + 2], s2);
    s3 = fmaf(xr[c + 3], wr[c + 3], s3);
  }
  float s = (s0 + s1) + (s2 + s3);
  s += bias[o];
  cls[qty * (BATCH * CDIM) + b * CDIM + d] = s;
}

// ---------- kernel W: W fp32 -> bf16 ----------
__global__ void wconv_kernel(const float* __restrict__ W, __bf16* __restrict__ wh) {
  int i = (blockIdx.x * 256 + threadIdx.x) * 4;  // grid covers 2304*768 exactly
  float4 v = *(const float4*)(W + i);
  bf16x4 o = {(__bf16)v.x, (__bf16)v.y, (__bf16)v.z, (__bf16)v.w};
  *(bf16x4*)(wh + i) = o;
}

// ---------- kernel B: MFMA bf16 QKV GEMM + m-write + Q/K/V chunk top-k ----------
__launch_bounds__(256, 2)
__global__ void fused_kernel(const float* __restrict__ x, const __bf16* __restrict__ wh,
                             const float* __restrict__ bias, const float* __restrict__ cls,
                             float* __restrict__ out,
                             float* __restrict__ candQ, float* __restrict__ candK,
                             unsigned* __restrict__ candV) {
  __shared__ __align__(16) union SM {
    struct { float xs[128 * 36]; __bf16 wsb[192 * 40]; } st;  // 18432 + 15360 B
    float bufq[128][68];                                      // 34816 B
    float part[4][64][13];
    unsigned partu[4][64][13];
  } sm;

  const int tid = threadIdx.x;
  const int dblk = blockIdx.x;   // 0..11 (fastest: consecutive blocks share x-tile)
  const int chunk = blockIdx.y;  // 0..31
  const int b = blockIdx.z;      // 0..3
  const int d0 = dblk * 64;
  const int w = tid >> 6, l = tid & 63;
  const int wr = w >> 1, wc = w & 1;   // wave 2x2 grid over (rows, cols)
  const int lg = l >> 4, lc = l & 15;  // lane group / lane col
  const int sq = tid >> 6, sd = tid & 63;  // scan roles

  // ---- precompute staging (slot -> source offset), k0/sub-independent parts
  unsigned soff[9];
#pragma unroll
  for (int i = 0; i < 9; ++i) {
    int sblk = w + 4 * i;
    unsigned off = 0;
    if (sblk < 18) {            // x region: 1152 slots, 9 slots per 128-row
      int sl = sblk * 64 + l;
      int row = sl / 9, o = sl % 9;
      if (o > 7) o = 7;         // pad slot duplicates slot 7 (in-bounds)
      off = (unsigned)(row * (CDIM * 4) + o * 16);
    } else if (sblk < 33) {     // W region: 960 slots, 5 per row, 192 rows
      int wsl = sblk * 64 + l - 1152;
      int row = wsl / 5, o = wsl % 5;
      if (o > 3) o = 3;
      int qty = row >> 6, dl = row & 63;
      off = (unsigned)(((qty * CDIM + d0 + dl) * CDIM) * 2 + o * 16);
    }
    soff[i] = off;
  }
  const char* whbase = (const char*)wh;

  // per-lane cls/bias constants for its 2 column groups
  float qc2[2], kc2[2], iv2[2], bq2[2], bk2[2], bv2[2];
#pragma unroll
  for (int tc = 0; tc < 2; ++tc) {
    int d = d0 + wc * 32 + tc * 16 + lc;
    float q_ = cls[0 * (BATCH * CDIM) + b * CDIM + d];
    float k_ = cls[1 * (BATCH * CDIM) + b * CDIM + d];
    float v_ = cls[2 * (BATCH * CDIM) + b * CDIM + d];
    qc2[tc] = q_; kc2[tc] = k_;
    iv2[tc] = (q_ * k_) * (1.0f + fabsf(v_));
    bq2[tc] = bias[d]; bk2[tc] = bias[CDIM + d]; bv2[tc] = bias[2 * CDIM + d];
  }

  // persistent Q/K per-thread quarter lists (across subs)
  float tqp[TOPK], tkp[TOPK];
#pragma unroll
  for (int r = 0; r < TOPK; ++r) { tqp[r] = -INFINITY; tkp[r] = -INFINITY; }

  for (int sub = 0; sub < 2; ++sub) {
    const int n0 = 1 + chunk * 256 + sub * 128;
    const char* xbase = (const char*)x + (size_t)(b * NSEQ + n0) * (CDIM * 4);

    f32x4 acc[4][2][3];
    const f32x4 zz = {0.f, 0.f, 0.f, 0.f};
#pragma unroll
    for (int rt = 0; rt < 4; ++rt)
#pragma unroll
      for (int tc = 0; tc < 2; ++tc)
#pragma unroll
        for (int q = 0; q < 3; ++q) acc[rt][tc][q] = zz;

    for (int k0 = 0; k0 < CDIM; k0 += 32) {
      __syncthreads();  // previous phase's LDS reads done
      // ---- stage x (fp32, padded rows) + W (bf16, padded rows) via global_load_lds
#pragma unroll
      for (int i = 0; i < 9; ++i) {
        int sblk = w + 4 * i;
        if (sblk < 33) {
          const char* src = (sblk < 18) ? (xbase + soff[i] + (unsigned)(k0 * 4))
                                        : (whbase + soff[i] + (unsigned)(k0 * 2));
          __builtin_amdgcn_global_load_lds(
              (const __attribute__((address_space(1))) unsigned*)(const void*)src,
              (__attribute__((address_space(3))) unsigned*)((__attribute__((address_space(3))) char*)&sm + sblk * 1024),
              16, 0, 0);
        }
      }
      __syncthreads();  // loads drained (compiler emits vmcnt(0) before barrier)

      // ---- fragments + MFMA
      bf16x8 bfr[2][3];
#pragma unroll
      for (int tc = 0; tc < 2; ++tc)
#pragma unroll
        for (int q = 0; q < 3; ++q)
          bfr[tc][q] = *(const bf16x8*)&sm.st.wsb[(q * 64 + wc * 32 + tc * 16 + lc) * 40 + lg * 8];
#pragma unroll
      for (int rt = 0; rt < 4; ++rt) {
        const float* xr = &sm.st.xs[(wr * 64 + rt * 16 + lc) * 36 + lg * 8];
        float4 a0 = *(const float4*)xr;
        float4 a1 = *(const float4*)(xr + 4);
        bf16x8 af;
        af[0] = (__bf16)a0.x; af[1] = (__bf16)a0.y; af[2] = (__bf16)a0.z; af[3] = (__bf16)a0.w;
        af[4] = (__bf16)a1.x; af[5] = (__bf16)a1.y; af[6] = (__bf16)a1.z; af[7] = (__bf16)a1.w;
#pragma unroll
        for (int tc = 0; tc < 2; ++tc)
#pragma unroll
          for (int q = 0; q < 3; ++q)
            acc[rt][tc][q] = __builtin_amdgcn_mfma_f32_16x16x32_bf16(af, bfr[tc][q], acc[rt][tc][q], 0, 0, 0);
      }
    }

    // ---- bias
#pragma unroll
    for (int rt = 0; rt < 4; ++rt)
#pragma unroll
      for (int tc = 0; tc < 2; ++tc)
#pragma unroll
        for (int r = 0; r < 4; ++r) {
          acc[rt][tc][0][r] += bq2[tc];
          acc[rt][tc][1][r] += bk2[tc];
          acc[rt][tc][2][r] += bv2[tc];
        }

    // ======== pass V: m = v^2+2v+iv -> bufq; scan; write out; merge candidates
    __syncthreads();  // last GEMM-phase LDS reads done before bufq overwrite
#pragma unroll
    for (int rt = 0; rt < 4; ++rt)
#pragma unroll
      for (int tc = 0; tc < 2; ++tc)
#pragma unroll
        for (int r = 0; r < 4; ++r) {
          float v = acc[rt][tc][2][r];
          sm.bufq[wr * 64 + rt * 16 + lg * 4 + r][wc * 32 + tc * 16 + lc] = fmaf(v, v + 2.0f, iv2[tc]);
        }
    __syncthreads();
    unsigned tv[PCV];
#pragma unroll
    for (int r = 0; r < PCV; ++r) tv[r] = 0u;
    {
      const int gb = chunk * 256 + sub * 128;
      for (int t = sq * 32; t < sq * 32 + 32; ++t)
        ins_u<PCV>(sortkey(sm.bufq[t][sd], gb + t), tv);
    }
    {  // m-map -> out (rows 1..8192)
      int row = tid >> 1, h = tid & 1;
      float* orow = out + ((size_t)(b * NSEQ + n0 + row)) * CDIM + d0 + h * 32;
#pragma unroll
      for (int i = 0; i < 8; ++i)
        *(float4*)(orow + i * 4) = *(const float4*)&sm.bufq[row][h * 32 + i * 4];
    }
    __syncthreads();
#pragma unroll
    for (int r = 0; r < PCV; ++r) sm.partu[sq][sd][r] = tv[r];
    __syncthreads();
    if (tid < 64) {
      for (int qq = 1; qq < 4; ++qq)
#pragma unroll
        for (int r = 0; r < PCV; ++r) ins_u<PCV>(sm.partu[qq][tid][r], tv);
      size_t base = ((size_t)(b * CDIM + d0 + tid) * NSUB + (chunk * 2 + sub)) * PCV;
#pragma unroll
      for (int r = 0; r < PCV; ++r) candV[base + r] = tv[r];
    }

    // ======== pass Q: a_q = q_cls*k + q
    __syncthreads();
#pragma unroll
    for (int rt = 0; rt < 4; ++rt)
#pragma unroll
      for (int tc = 0; tc < 2; ++tc)
#pragma unroll
        for (int r = 0; r < 4; ++r)
          sm.bufq[wr * 64 + rt * 16 + lg * 4 + r][wc * 32 + tc * 16 + lc] =
              fmaf(qc2[tc], acc[rt][tc][1][r], acc[rt][tc][0][r]);
    __syncthreads();
    for (int t = sq * 32; t < sq * 32 + 32; ++t) ins_f(sm.bufq[t][sd], tqp);

    // ======== pass K: a_k = k_cls*q + k
    __syncthreads();
#pragma unroll
    for (int rt = 0; rt < 4; ++rt)
#pragma unroll
      for (int tc = 0; tc < 2; ++tc)
#pragma unroll
        for (int r = 0; r < 4; ++r)
          sm.bufq[wr * 64 + rt * 16 + lg * 4 + r][wc * 32 + tc * 16 + lc] =
              fmaf(kc2[tc], acc[rt][tc][0][r], acc[rt][tc][1][r]);
    __syncthreads();
    for (int t = sq * 32; t < sq * 32 + 32; ++t) ins_f(sm.bufq[t][sd], tkp);
    // loop-top barrier of next sub protects staging overwrite of bufq
  }

  // ---- merge Q partials, write candQ
  __syncthreads();
#pragma unroll
  for (int r = 0; r < TOPK; ++r) sm.part[sq][sd][r] = tqp[r];
  __syncthreads();
  if (tid < 64) {
    for (int qq = 1; qq < 4; ++qq)
#pragma unroll
      for (int r = 0; r < TOPK; ++r) ins_f(sm.part[qq][tid][r], tqp);
    size_t base = ((size_t)(b * CDIM + d0 + tid) * NCHUNK + chunk) * TOPK;
#pragma unroll
    for (int r = 0; r < TOPK; ++r) candQ[base + r] = tqp[r];
  }
  // ---- merge K partials, write candK
  __syncthreads();
#pragma unroll
  for (int r = 0; r < TOPK; ++r) sm.part[sq][sd][r] = tkp[r];
  __syncthreads();
  if (tid < 64) {
    for (int qq = 1; qq < 4; ++qq)
#pragma unroll
      for (int r = 0; r < TOPK; ++r) ins_f(sm.part[qq][tid][r], tkp);
    size_t base = ((size_t)(b * CDIM + d0 + tid) * NCHUNK + chunk) * TOPK;
#pragma unroll
    for (int r = 0; r < TOPK; ++r) candK[base + r] = tkp[r];
  }
}

// ---------- kernel E: merge V subchunk candidates -> global top-32 indices ----------
__global__ void vmerge_kernel(const unsigned* __restrict__ candV, int* __restrict__ cVi) {
  __shared__ unsigned pu[4][64][NCAND];
  const int tid = threadIdx.x;
  const int q = tid >> 6, c = tid & 63;
  const int pr = blockIdx.x * 64 + c;
  unsigned lv[NCAND];
#pragma unroll
  for (int r = 0; r < NCAND; ++r) lv[r] = 0u;
  size_t base = ((size_t)pr * NSUB + q * 16) * PCV;
  for (int i = 0; i < 16 * PCV; ++i) ins_u<NCAND>(candV[base + i], lv);
#pragma unroll
  for (int r = 0; r < NCAND; ++r) pu[q][c][r] = lv[r];
  __syncthreads();
  if (tid < 64) {
    for (int qq = 1; qq < 4; ++qq)
#pragma unroll
      for (int r = 0; r < NCAND; ++r) ins_u<NCAND>(pu[qq][tid][r], lv);
    size_t ob = (size_t)(blockIdx.x * 64 + tid) * NCAND;
#pragma unroll
    for (int r = 0; r < NCAND; ++r) cVi[ob + r] = (int)(lv[r] & 0x1FFFu);
  }
}

// ---------- kernel C: merge Q/K chunk candidates -> qm/km rows; cls row 0 ----------
__global__ void merge_qk_kernel(const float* __restrict__ cls,
                                const float* __restrict__ candQ, const float* __restrict__ candK,
                                float* __restrict__ qm, float* __restrict__ km,
                                float* __restrict__ vm) {
  __shared__ float pq[4][64][13];
  __shared__ float pk[4][64][13];
  const int tid = threadIdx.x;
  const int pr = blockIdx.x * 64 + (tid & 63);
  const int q = tid >> 6;
  float tq[TOPK], tk[TOPK];
#pragma unroll
  for (int r = 0; r < TOPK; ++r) { tq[r] = -INFINITY; tk[r] = -INFINITY; }
  size_t base = ((size_t)pr * NCHUNK + q * 8) * TOPK;
  for (int c = 0; c < 8 * TOPK; ++c) {
    ins_f(candQ[base + c], tq);
    ins_f(candK[base + c], tk);
  }
#pragma unroll
  for (int r = 0; r < TOPK; ++r) { pq[q][tid & 63][r] = tq[r]; pk[q][tid & 63][r] = tk[r]; }
  __syncthreads();
  if (tid < 64) {
    for (int qq = 1; qq < 4; ++qq)
#pragma unroll
      for (int r = 0; r < TOPK; ++r) { ins_f(pq[qq][tid][r], tq); ins_f(pk[qq][tid][r], tk); }
    int pr2 = blockIdx.x * 64 + tid;
    int b = pr2 / CDIM, d = pr2 % CDIM;
    qm[(size_t)(b * 13 + 0) * CDIM + d] = cls[0 * (BATCH * CDIM) + b * CDIM + d];
    km[(size_t)(b * 13 + 0) * CDIM + d] = cls[1 * (BATCH * CDIM) + b * CDIM + d];
    vm[(size_t)(b * 13 + 0) * CDIM + d] = cls[2 * (BATCH * CDIM) + b * CDIM + d];
#pragma unroll
    for (int r = 0; r < TOPK; ++r) {
      qm[(size_t)(b * 13 + 1 + r) * CDIM + d] = tq[r];
      km[(size_t)(b * 13 + 1 + r) * CDIM + d] = tk[r];
    }
  }
}

// ---------- kernel F: fp64 rescoring of the 32 V candidates -> exact top-12 ----------
__global__ void rescore_kernel(const float* __restrict__ x, const float* __restrict__ W,
                               const float* __restrict__ bias, const float* __restrict__ cls,
                               const int* __restrict__ cVi,
                               float* __restrict__ vm, int* __restrict__ vidx) {
  const int d = blockIdx.x;
  const int b = blockIdx.y;
  const int tid = threadIdx.x;
  __shared__ int sidx[NCAND];
  __shared__ double spart[NCAND][9];
  if (tid < NCAND) sidx[tid] = cVi[((size_t)b * CDIM + d) * NCAND + tid];
  __syncthreads();
  const int c = tid >> 3, e = tid & 7;
  const float* xr = x + ((size_t)b * NSEQ + 1 + sidx[c]) * CDIM + e * 96;
  const float* wr = W + (size_t)(2 * CDIM + d) * CDIM + e * 96;
  double s = 0.0;
#pragma unroll 4
  for (int j = 0; j < 96; ++j) s = fma((double)xr[j], (double)wr[j], s);
  spart[c][e] = s;
  __syncthreads();
  if (tid < NCAND) {
    double v = 0.0;
    for (int ee = 0; ee < 8; ++ee) v += spart[tid][ee];  // fixed order
    v += (double)bias[2 * CDIM + d];
    double qc = (double)cls[0 * (BATCH * CDIM) + b * CDIM + d];
    double kc = (double)cls[1 * (BATCH * CDIM) + b * CDIM + d];
    double vc = (double)cls[2 * (BATCH * CDIM) + b * CDIM + d];
    double ivd = (qc * kc) * (1.0 + fabs(vc));
    spart[tid][8] = fma(v, v + 2.0, ivd);
  }
  __syncthreads();
  if (tid == 0) {
    double lv[TOPK];
    int li[TOPK];
#pragma unroll
    for (int r = 0; r < TOPK; ++r) { lv[r] = -INFINITY; li[r] = 0x7fffffff; }
    for (int cc = 0; cc < NCAND; ++cc) ins_di(spart[cc][8], sidx[cc], lv, li);
#pragma unroll
    for (int r = 0; r < TOPK; ++r) {
      vm[(size_t)(b * 13 + 1 + r) * CDIM + d] = (float)lv[r];
      vidx[(size_t)(b * TOPK + r) * CDIM + d] = li[r];
    }
  }
}

// ---------- kernel D: 13x13 attention + scatter-add ----------
__global__ void attn_kernel(const float* __restrict__ qm, const float* __restrict__ km,
                            const float* __restrict__ vm, const int* __restrict__ vidx,
                            float* __restrict__ out) {
  const int b = blockIdx.x, tid = threadIdx.x;
  __shared__ float att[13][16];
  if (tid < 169) {
    int i = tid / 13, j = tid % 13;
    const float* qr = qm + (size_t)(b * 13 + i) * CDIM;
    const float* kr = km + (size_t)(b * 13 + j) * CDIM;
    float s0 = 0.f, s1 = 0.f, s2 = 0.f, s3 = 0.f;
    for (int c = 0; c < CDIM; c += 4) {
      s0 = fmaf(qr[c + 0], kr[c + 0], s0);
      s1 = fmaf(qr[c + 1], kr[c + 1], s1);
      s2 = fmaf(qr[c + 2], kr[c + 2], s2);
      s3 = fmaf(qr[c + 3], kr[c + 3], s3);
    }
    att[i][j] = ((s0 + s1) + (s2 + s3)) * 0.03608439182435161f;  // 768^-0.5
  }
  __syncthreads();
  if (tid < 13) {
    float mx = -INFINITY;
    float e[13];
#pragma unroll
    for (int j = 0; j < 13; ++j) mx = fmaxf(mx, att[tid][j]);
    float sum = 0.f;
#pragma unroll
    for (int j = 0; j < 13; ++j) { e[j] = expf(att[tid][j] - mx); sum += e[j]; }
    float inv = 1.f / sum;
#pragma unroll
    for (int j = 0; j < 13; ++j) att[tid][j] = e[j] * inv;
  }
  __syncthreads();
  for (int i = tid; i < 13 * CDIM; i += 256) {
    int j = i / CDIM, d = i % CDIM;
    float s = 0.f;
#pragma unroll
    for (int kk = 0; kk < 13; ++kk) s = fmaf(att[j][kk], vm[(size_t)(b * 13 + kk) * CDIM + d], s);
    if (j == 0) {
      out[(size_t)b * NSEQ * CDIM + d] = s;
    } else {
      int t = vidx[(size_t)(b * TOPK + (j - 1)) * CDIM + d];
      out[((size_t)b * NSEQ + 1 + t) * CDIM + d] += s;
    }
  }
}

extern "C" void kernel_launch(void* const* d_in, const int* in_sizes, int n_in,
                              void* d_out, int out_size, void* d_ws, size_t ws_size,
                              hipStream_t stream) {
  const float* x = (const float*)d_in[0];
  const float* W = (const float*)d_in[1];
  const float* bias = (const float*)d_in[2];
  float* out = (float*)d_out;
  char* ws = (char*)d_ws;

  float* cls = (float*)(ws + 0);               // 36864
  float* qm = (float*)(ws + 36864);            // 159744
  float* km = (float*)(ws + 196608);           // 159744
  float* vm = (float*)(ws + 356352);           // 159744
  int* vidx = (int*)(ws + 516096);             // 147456
  float* candQ = (float*)(ws + 663552);        // 4718592
  float* candK = (float*)(ws + 5382144);       // 4718592
  unsigned* candV = (unsigned*)(ws + 10100736);// 9437184
  int* cVi = (int*)(ws + 19537920);            // 393216
  __bf16* wh = (__bf16*)(ws + 19931136);       // 3538944 -> total 23470080

  hipLaunchKernelGGL(cls_kernel, dim3(36), dim3(256), 0, stream, x, W, bias, cls);
  hipLaunchKernelGGL(wconv_kernel, dim3(1728), dim3(256), 0, stream, W, wh);
  hipLaunchKernelGGL(fused_kernel, dim3(NDBLK, NCHUNK, BATCH), dim3(256), 0, stream,
                     x, wh, bias, cls, out, candQ, candK, candV);
  hipLaunchKernelGGL(vmerge_kernel, dim3(BATCH * CDIM / 64), dim3(256), 0, stream, candV, cVi);
  hipLaunchKernelGGL(merge_qk_kernel, dim3(BATCH * CDIM / 64), dim3(256), 0, stream,
                     cls, candQ, candK, qm, km, vm);
  hipLaunchKernelGGL(rescore_kernel, dim3(CDIM, BATCH), dim3(256), 0, stream,
                     x, W, bias, cls, cVi, vm, vidx);
  hipLaunchKernelGGL(attn_kernel, dim3(BATCH), dim3(256), 0, stream, qm, km, vm, vidx, out);
}

// Round 7
// 667.430 us; speedup vs baseline: 5.5204x; 1.1573x over previous
//
#include <hip/hip_runtime.h>
#include <math.h>

#define BATCH 4
#define NSEQ 8193
#define CDIM 768
#define TOPK 12
#define NCHUNK 32      // 32 chunks x 256 tokens (2 subs of 128)
#define NSUB 64        // 64 subchunks x 128 tokens (V candidate granularity)
#define PCV 12         // per-subchunk V candidates (packed u32)
#define NCAND 32       // global V candidates, fp64-rescored
#define NDBLK 12       // 768 / 64
#define KSTEP 32
#define NT 24          // 768/32
#define ROWSTRIDE 40   // bf16 elems per LDS row (32 data + 8 pad = 80B, 2-way-bank-safe)
#define STGE 12800     // bf16 elems per staging buffer: 320 rows * 40

typedef __attribute__((ext_vector_type(8))) __bf16 bf16x8;
typedef __attribute__((ext_vector_type(4))) __bf16 bf16x4;
typedef __attribute__((ext_vector_type(4))) float f32x4;

// ---------- top-k insertion helpers ----------
__device__ __forceinline__ void ins_f(float v, float (&lst)[TOPK]) {
  if (v > lst[TOPK - 1]) {
#pragma unroll
    for (int r = 0; r < TOPK; ++r) {
      bool g = v > lst[r];
      float disp = g ? lst[r] : v;
      lst[r] = g ? v : lst[r];
      v = disp;
    }
  }
}

template <int DP>
__device__ __forceinline__ void ins_u(unsigned v, unsigned (&lst)[DP]) {
  if (v > lst[DP - 1]) {
#pragma unroll
    for (int r = 0; r < DP; ++r) {
      bool g = v > lst[r];
      unsigned dv = g ? lst[r] : v;
      lst[r] = g ? v : lst[r];
      v = dv;
    }
  }
}

__device__ __forceinline__ void ins_di(double v, int i, double (&lv)[TOPK], int (&li)[TOPK]) {
#pragma unroll
  for (int r = 0; r < TOPK; ++r) {
    bool g = (v > lv[r]) || (v == lv[r] && i < li[r]);
    double dv = g ? lv[r] : v;
    int di = g ? li[r] : i;
    lv[r] = g ? v : lv[r];
    li[r] = g ? i : li[r];
    v = dv;
    i = di;
  }
}

// value-ordered sortable key with embedded token index (13 bits)
__device__ __forceinline__ unsigned sortkey(float f, int idx) {
  unsigned u = __float_as_uint(f);
  u = (u & 0x80000000u) ? ~u : (u | 0x80000000u);
  return (u & 0xFFFFE000u) | (unsigned)idx;
}

// ---------- kernel A: cls-token QKV rows (token 0), fp32 ----------
__global__ void cls_kernel(const float* __restrict__ x, const float* __restrict__ W,
                           const float* __restrict__ bias, float* __restrict__ cls) {
  int idx = blockIdx.x * 256 + threadIdx.x;
  if (idx >= 3 * BATCH * CDIM) return;
  int qty = idx / (BATCH * CDIM);
  int rem = idx % (BATCH * CDIM);
  int b = rem / CDIM;
  int d = rem % CDIM;
  int o = qty * CDIM + d;
  const float* xr = x + (size_t)b * NSEQ * CDIM;
  const float* wr = W + (size_t)o * CDIM;
  float s0 = 0.f, s1 = 0.f, s2 = 0.f, s3 = 0.f;
  for (int c = 0; c < CDIM; c += 4) {
    s0 = fmaf(xr[c + 0], wr[c + 0], s0);
    s1 = fmaf(xr[c + 1], wr[c + 1], s1);
    s2 = fmaf(xr[c + 2], wr[c + 2], s2);
    s3 = fmaf(xr[c + 3], wr[c + 3], s3);
  }
  float s = (s0 + s1) + (s2 + s3);
  s += bias[o];
  cls[qty * (BATCH * CDIM) + b * CDIM + d] = s;
}

// ---------- kernel W: W fp32 -> bf16 ----------
__global__ void wconv_kernel(const float* __restrict__ W, __bf16* __restrict__ wh) {
  int i = (blockIdx.x * 256 + threadIdx.x) * 4;  // grid covers 2304*768 exactly
  float4 v = *(const float4*)(W + i);
  bf16x4 o = {(__bf16)v.x, (__bf16)v.y, (__bf16)v.z, (__bf16)v.w};
  *(bf16x4*)(wh + i) = o;
}

// ---------- kernel B: MFMA bf16 GEMM, reg-staged cvt-once double-buffered pipeline ----------
__launch_bounds__(256, 2)
__global__ void fused_kernel(const float* __restrict__ x, const __bf16* __restrict__ wh,
                             const float* __restrict__ bias, const float* __restrict__ cls,
                             float* __restrict__ out,
                             float* __restrict__ candQ, float* __restrict__ candK,
                             unsigned* __restrict__ candV) {
  __shared__ __align__(16) union SM {
    __bf16 stg[2][STGE];          // 2 x 25600B; rows 0..127 = x tokens, 128..319 = W rows
    float bufq[128][68];          // 34816B epilogue redistribution
    float part[4][64][13];
    unsigned partu[4][64][13];
  } sm;

  const int tid = threadIdx.x;
  const int dblk = blockIdx.x, chunk = blockIdx.y, b = blockIdx.z;
  const int d0 = dblk * 64;
  const int w = tid >> 6, l = tid & 63;
  const int wr = w >> 1, wc = w & 1;   // wave 2x2 over (row-tiles, col-halves)
  const int lg = l >> 4, lc = l & 15;
  const int sq = tid >> 6, sd = tid & 63;

  // staging roles (k0-independent)
  const int xrow = tid >> 1, xh_ = tid & 1;        // x: row 0..127, 16-float half
  // W slots: s = tid + i*256, i=0..2 -> row = s>>2 (0..191), o = s&3
  const __bf16* wbase = wh;

  // per-lane cls/bias constants for its 2 column groups
  float qc2[2], kc2[2], iv2[2], bq2[2], bk2[2], bv2[2];
#pragma unroll
  for (int tc = 0; tc < 2; ++tc) {
    int d = d0 + wc * 32 + tc * 16 + lc;
    float q_ = cls[0 * (BATCH * CDIM) + b * CDIM + d];
    float k_ = cls[1 * (BATCH * CDIM) + b * CDIM + d];
    float v_ = cls[2 * (BATCH * CDIM) + b * CDIM + d];
    qc2[tc] = q_; kc2[tc] = k_;
    iv2[tc] = (q_ * k_) * (1.0f + fabsf(v_));
    bq2[tc] = bias[d]; bk2[tc] = bias[CDIM + d]; bv2[tc] = bias[2 * CDIM + d];
  }

  // persistent Q/K per-thread quarter lists (across subs), like R5
  float tqp[TOPK], tkp[TOPK];
#pragma unroll
  for (int r = 0; r < TOPK; ++r) { tqp[r] = -INFINITY; tkp[r] = -INFINITY; }

  for (int sub = 0; sub < 2; ++sub) {
    const int n0 = 1 + chunk * 256 + sub * 128;
    const float* xrp = x + (size_t)(b * NSEQ + n0 + xrow) * CDIM;  // this thread's x row

    f32x4 acc[4][2][3];
    const f32x4 zz = {0.f, 0.f, 0.f, 0.f};
#pragma unroll
    for (int rt = 0; rt < 4; ++rt)
#pragma unroll
      for (int tc = 0; tc < 2; ++tc)
#pragma unroll
        for (int q = 0; q < 3; ++q) acc[rt][tc][q] = zz;

    // staging registers
    float4 xa0, xa1, xa2, xa3;
    bf16x8 wv0, wv1, wv2;

#define LOADT(T)                                                                      \
    {                                                                                 \
      const float* xp = xrp + (T) * KSTEP + xh_ * 16;                                 \
      xa0 = *(const float4*)(xp + 0);                                                 \
      xa1 = *(const float4*)(xp + 4);                                                 \
      xa2 = *(const float4*)(xp + 8);                                                 \
      xa3 = *(const float4*)(xp + 12);                                                \
      {                                                                               \
        int s0_ = tid, r0 = s0_ >> 2, o0 = s0_ & 3;                                   \
        wv0 = *(const bf16x8*)(wbase + ((size_t)((r0 >> 6) * CDIM + d0 + (r0 & 63))) * CDIM + (T) * KSTEP + o0 * 8); \
        int s1_ = tid + 256, r1 = s1_ >> 2, o1 = s1_ & 3;                             \
        wv1 = *(const bf16x8*)(wbase + ((size_t)((r1 >> 6) * CDIM + d0 + (r1 & 63))) * CDIM + (T) * KSTEP + o1 * 8); \
        int s2_ = tid + 512, r2 = s2_ >> 2, o2 = s2_ & 3;                             \
        wv2 = *(const bf16x8*)(wbase + ((size_t)((r2 >> 6) * CDIM + d0 + (r2 & 63))) * CDIM + (T) * KSTEP + o2 * 8); \
      }                                                                               \
    }

#define CVTWR(NB)                                                                     \
    {                                                                                 \
      __bf16* base_ = &sm.stg[NB][0];                                                 \
      bf16x8 lo, hi;                                                                  \
      lo[0] = (__bf16)xa0.x; lo[1] = (__bf16)xa0.y; lo[2] = (__bf16)xa0.z; lo[3] = (__bf16)xa0.w; \
      lo[4] = (__bf16)xa1.x; lo[5] = (__bf16)xa1.y; lo[6] = (__bf16)xa1.z; lo[7] = (__bf16)xa1.w; \
      hi[0] = (__bf16)xa2.x; hi[1] = (__bf16)xa2.y; hi[2] = (__bf16)xa2.z; hi[3] = (__bf16)xa2.w; \
      hi[4] = (__bf16)xa3.x; hi[5] = (__bf16)xa3.y; hi[6] = (__bf16)xa3.z; hi[7] = (__bf16)xa3.w; \
      *(bf16x8*)(base_ + xrow * ROWSTRIDE + xh_ * 16) = lo;                           \
      *(bf16x8*)(base_ + xrow * ROWSTRIDE + xh_ * 16 + 8) = hi;                       \
      int s0_ = tid, r0 = s0_ >> 2, o0 = s0_ & 3;                                     \
      *(bf16x8*)(base_ + (128 + r0) * ROWSTRIDE + o0 * 8) = wv0;                      \
      int s1_ = tid + 256, r1 = s1_ >> 2, o1 = s1_ & 3;                               \
      *(bf16x8*)(base_ + (128 + r1) * ROWSTRIDE + o1 * 8) = wv1;                      \
      int s2_ = tid + 512, r2 = s2_ >> 2, o2 = s2_ & 3;                               \
      *(bf16x8*)(base_ + (128 + r2) * ROWSTRIDE + o2 * 8) = wv2;                      \
    }

    __syncthreads();  // stg region free of prior-phase (bufq) use
    LOADT(0);
    CVTWR(0);         // data-dep waits on its own loads only
    for (int t = 0; t < NT; ++t) {
      __syncthreads();  // buf[t&1] writes visible; prior reads done
      if (t + 1 < NT) LOADT(t + 1);   // issue next-tile global loads early
      {
        const __bf16* smc = &sm.stg[t & 1][0];
        bf16x8 bfr[2][3];
#pragma unroll
        for (int tc = 0; tc < 2; ++tc)
#pragma unroll
          for (int q = 0; q < 3; ++q)
            bfr[tc][q] = *(const bf16x8*)(smc + (128 + q * 64 + wc * 32 + tc * 16 + lc) * ROWSTRIDE + lg * 8);
#pragma unroll
        for (int rt = 0; rt < 4; ++rt) {
          bf16x8 af = *(const bf16x8*)(smc + (wr * 64 + rt * 16 + lc) * ROWSTRIDE + lg * 8);
#pragma unroll
          for (int tc = 0; tc < 2; ++tc)
#pragma unroll
            for (int q = 0; q < 3; ++q)
              acc[rt][tc][q] = __builtin_amdgcn_mfma_f32_16x16x32_bf16(af, bfr[tc][q], acc[rt][tc][q], 0, 0, 0);
        }
      }
      if (t + 1 < NT) CVTWR((t + 1) & 1);  // write other buffer (disjoint from reads)
    }
#undef LOADT
#undef CVTWR
    __syncthreads();  // last tile's ds_reads done before bufq overwrite

    // bias
#pragma unroll
    for (int rt = 0; rt < 4; ++rt)
#pragma unroll
      for (int tc = 0; tc < 2; ++tc)
#pragma unroll
        for (int r = 0; r < 4; ++r) {
          acc[rt][tc][0][r] += bq2[tc];
          acc[rt][tc][1][r] += bk2[tc];
          acc[rt][tc][2][r] += bv2[tc];
        }

    // ======== pass V: m = v^2+2v+iv (epilogue identical to R5)
#pragma unroll
    for (int rt = 0; rt < 4; ++rt)
#pragma unroll
      for (int tc = 0; tc < 2; ++tc)
#pragma unroll
        for (int r = 0; r < 4; ++r) {
          float v = acc[rt][tc][2][r];
          sm.bufq[wr * 64 + rt * 16 + lg * 4 + r][wc * 32 + tc * 16 + lc] = fmaf(v, v + 2.0f, iv2[tc]);
        }
    __syncthreads();
    unsigned tv[PCV];
#pragma unroll
    for (int r = 0; r < PCV; ++r) tv[r] = 0u;
    {
      const int gb = chunk * 256 + sub * 128;
      for (int t = sq * 32; t < sq * 32 + 32; ++t)
        ins_u<PCV>(sortkey(sm.bufq[t][sd], gb + t), tv);
    }
    {  // m-map -> out rows
      int row = tid >> 1, h = tid & 1;
      float* orow = out + ((size_t)(b * NSEQ + n0 + row)) * CDIM + d0 + h * 32;
#pragma unroll
      for (int i = 0; i < 8; ++i)
        *(float4*)(orow + i * 4) = *(const float4*)&sm.bufq[row][h * 32 + i * 4];
    }
    __syncthreads();
#pragma unroll
    for (int r = 0; r < PCV; ++r) sm.partu[sq][sd][r] = tv[r];
    __syncthreads();
    if (tid < 64) {
      for (int qq = 1; qq < 4; ++qq)
#pragma unroll
        for (int r = 0; r < PCV; ++r) ins_u<PCV>(sm.partu[qq][tid][r], tv);
      size_t base = ((size_t)(b * CDIM + d0 + tid) * NSUB + (chunk * 2 + sub)) * PCV;
#pragma unroll
      for (int r = 0; r < PCV; ++r) candV[base + r] = tv[r];
    }

    // ======== pass Q: a_q = q_cls*k + q
    __syncthreads();
#pragma unroll
    for (int rt = 0; rt < 4; ++rt)
#pragma unroll
      for (int tc = 0; tc < 2; ++tc)
#pragma unroll
        for (int r = 0; r < 4; ++r)
          sm.bufq[wr * 64 + rt * 16 + lg * 4 + r][wc * 32 + tc * 16 + lc] =
              fmaf(qc2[tc], acc[rt][tc][1][r], acc[rt][tc][0][r]);
    __syncthreads();
    for (int t = sq * 32; t < sq * 32 + 32; ++t) ins_f(sm.bufq[t][sd], tqp);

    // ======== pass K: a_k = k_cls*q + k
    __syncthreads();
#pragma unroll
    for (int rt = 0; rt < 4; ++rt)
#pragma unroll
      for (int tc = 0; tc < 2; ++tc)
#pragma unroll
        for (int r = 0; r < 4; ++r)
          sm.bufq[wr * 64 + rt * 16 + lg * 4 + r][wc * 32 + tc * 16 + lc] =
              fmaf(kc2[tc], acc[rt][tc][0][r], acc[rt][tc][1][r]);
    __syncthreads();
    for (int t = sq * 32; t < sq * 32 + 32; ++t) ins_f(sm.bufq[t][sd], tkp);
    // next sub's top barrier protects stg overwrite of bufq
  }  // sub

  // ---- merge Q partials, write candQ (chunk granularity, R5-verbatim)
  __syncthreads();
#pragma unroll
  for (int r = 0; r < TOPK; ++r) sm.part[sq][sd][r] = tqp[r];
  __syncthreads();
  if (tid < 64) {
    for (int qq = 1; qq < 4; ++qq)
#pragma unroll
      for (int r = 0; r < TOPK; ++r) ins_f(sm.part[qq][tid][r], tqp);
    size_t base = ((size_t)(b * CDIM + d0 + tid) * NCHUNK + chunk) * TOPK;
#pragma unroll
    for (int r = 0; r < TOPK; ++r) candQ[base + r] = tqp[r];
  }
  // ---- merge K partials, write candK
  __syncthreads();
#pragma unroll
  for (int r = 0; r < TOPK; ++r) sm.part[sq][sd][r] = tkp[r];
  __syncthreads();
  if (tid < 64) {
    for (int qq = 1; qq < 4; ++qq)
#pragma unroll
      for (int r = 0; r < TOPK; ++r) ins_f(sm.part[qq][tid][r], tkp);
    size_t base = ((size_t)(b * CDIM + d0 + tid) * NCHUNK + chunk) * TOPK;
#pragma unroll
    for (int r = 0; r < TOPK; ++r) candK[base + r] = tkp[r];
  }
}

// ---------- kernel E: merge V subchunk candidates -> global top-32 indices (R5 verbatim) ----------
__global__ void vmerge_kernel(const unsigned* __restrict__ candV, int* __restrict__ cVi) {
  __shared__ unsigned pu[4][64][NCAND];
  const int tid = threadIdx.x;
  const int q = tid >> 6, c = tid & 63;
  const int pr = blockIdx.x * 64 + c;
  unsigned lv[NCAND];
#pragma unroll
  for (int r = 0; r < NCAND; ++r) lv[r] = 0u;
  size_t base = ((size_t)pr * NSUB + q * 16) * PCV;
  for (int i = 0; i < 16 * PCV; ++i) ins_u<NCAND>(candV[base + i], lv);
#pragma unroll
  for (int r = 0; r < NCAND; ++r) pu[q][c][r] = lv[r];
  __syncthreads();
  if (tid < 64) {
    for (int qq = 1; qq < 4; ++qq)
#pragma unroll
      for (int r = 0; r < NCAND; ++r) ins_u<NCAND>(pu[qq][tid][r], lv);
    size_t ob = (size_t)(blockIdx.x * 64 + tid) * NCAND;
#pragma unroll
    for (int r = 0; r < NCAND; ++r) cVi[ob + r] = (int)(lv[r] & 0x1FFFu);
  }
}

// ---------- kernel C: merge Q/K chunk candidates -> qm/km rows; cls row 0 (R5 verbatim) ----------
__global__ void merge_qk_kernel(const float* __restrict__ cls,
                                const float* __restrict__ candQ, const float* __restrict__ candK,
                                float* __restrict__ qm, float* __restrict__ km,
                                float* __restrict__ vm) {
  __shared__ float pq[4][64][13];
  __shared__ float pk[4][64][13];
  const int tid = threadIdx.x;
  const int pr = blockIdx.x * 64 + (tid & 63);
  const int q = tid >> 6;
  float tq[TOPK], tk[TOPK];
#pragma unroll
  for (int r = 0; r < TOPK; ++r) { tq[r] = -INFINITY; tk[r] = -INFINITY; }
  size_t base = ((size_t)pr * NCHUNK + q * 8) * TOPK;
  for (int c = 0; c < 8 * TOPK; ++c) {
    ins_f(candQ[base + c], tq);
    ins_f(candK[base + c], tk);
  }
#pragma unroll
  for (int r = 0; r < TOPK; ++r) { pq[q][tid & 63][r] = tq[r]; pk[q][tid & 63][r] = tk[r]; }
  __syncthreads();
  if (tid < 64) {
    for (int qq = 1; qq < 4; ++qq)
#pragma unroll
      for (int r = 0; r < TOPK; ++r) { ins_f(pq[qq][tid][r], tq); ins_f(pk[qq][tid][r], tk); }
    int pr2 = blockIdx.x * 64 + tid;
    int b = pr2 / CDIM, d = pr2 % CDIM;
    qm[(size_t)(b * 13 + 0) * CDIM + d] = cls[0 * (BATCH * CDIM) + b * CDIM + d];
    km[(size_t)(b * 13 + 0) * CDIM + d] = cls[1 * (BATCH * CDIM) + b * CDIM + d];
    vm[(size_t)(b * 13 + 0) * CDIM + d] = cls[2 * (BATCH * CDIM) + b * CDIM + d];
#pragma unroll
    for (int r = 0; r < TOPK; ++r) {
      qm[(size_t)(b * 13 + 1 + r) * CDIM + d] = tq[r];
      km[(size_t)(b * 13 + 1 + r) * CDIM + d] = tk[r];
    }
  }
}

// ---------- kernel F: fp64 rescoring (coalesced, wave-per-candidate) ----------
__global__ void rescore_kernel(const float* __restrict__ x, const float* __restrict__ W,
                               const float* __restrict__ bias, const float* __restrict__ cls,
                               const int* __restrict__ cVi,
                               float* __restrict__ vm, int* __restrict__ vidx) {
  const int d = blockIdx.x;
  const int b = blockIdx.y;
  const int tid = threadIdx.x, w = tid >> 6, l = tid & 63;
  __shared__ float wrow[CDIM];
  __shared__ int sidx[NCAND];
  __shared__ double sval[NCAND];
  if (tid < 192) *(float4*)&wrow[tid * 4] = *(const float4*)(W + (size_t)(2 * CDIM + d) * CDIM + tid * 4);
  if (tid >= 192 && tid < 192 + NCAND)
    sidx[tid - 192] = cVi[((size_t)b * CDIM + d) * NCAND + (tid - 192)];
  __syncthreads();
#pragma unroll
  for (int c8 = 0; c8 < NCAND / 4; ++c8) {
    const int c = w * (NCAND / 4) + c8;
    const float* xr = x + ((size_t)b * NSEQ + 1 + sidx[c]) * CDIM + l * 12;
    const float* wp = &wrow[l * 12];
    float4 a0 = *(const float4*)xr;
    float4 a1 = *(const float4*)(xr + 4);
    float4 a2 = *(const float4*)(xr + 8);
    double s = 0.0;
    s = fma((double)a0.x, (double)wp[0], s);
    s = fma((double)a0.y, (double)wp[1], s);
    s = fma((double)a0.z, (double)wp[2], s);
    s = fma((double)a0.w, (double)wp[3], s);
    s = fma((double)a1.x, (double)wp[4], s);
    s = fma((double)a1.y, (double)wp[5], s);
    s = fma((double)a1.z, (double)wp[6], s);
    s = fma((double)a1.w, (double)wp[7], s);
    s = fma((double)a2.x, (double)wp[8], s);
    s = fma((double)a2.y, (double)wp[9], s);
    s = fma((double)a2.z, (double)wp[10], s);
    s = fma((double)a2.w, (double)wp[11], s);
#pragma unroll
    for (int off = 32; off > 0; off >>= 1) s += __shfl_xor(s, off, 64);  // deterministic tree
    if (l == 0) sval[c] = s;
  }
  __syncthreads();
  if (tid < NCAND) {
    double v = sval[tid] + (double)bias[2 * CDIM + d];
    double qc = (double)cls[0 * (BATCH * CDIM) + b * CDIM + d];
    double kc = (double)cls[1 * (BATCH * CDIM) + b * CDIM + d];
    double vc = (double)cls[2 * (BATCH * CDIM) + b * CDIM + d];
    double ivd = (qc * kc) * (1.0 + fabs(vc));
    sval[tid] = fma(v, v + 2.0, ivd);
  }
  __syncthreads();
  if (tid == 0) {
    double lv[TOPK];
    int li[TOPK];
#pragma unroll
    for (int r = 0; r < TOPK; ++r) { lv[r] = -INFINITY; li[r] = 0x7fffffff; }
    for (int cc = 0; cc < NCAND; ++cc) ins_di(sval[cc], sidx[cc], lv, li);
#pragma unroll
    for (int r = 0; r < TOPK; ++r) {
      vm[(size_t)(b * 13 + 1 + r) * CDIM + d] = (float)lv[r];
      vidx[(size_t)(b * TOPK + r) * CDIM + d] = li[r];
    }
  }
}

// ---------- kernel D: 13x13 attention + scatter-add (R5 verbatim) ----------
__global__ void attn_kernel(const float* __restrict__ qm, const float* __restrict__ km,
                            const float* __restrict__ vm, const int* __restrict__ vidx,
                            float* __restrict__ out) {
  const int b = blockIdx.x, tid = threadIdx.x;
  __shared__ float att[13][16];
  if (tid < 169) {
    int i = tid / 13, j = tid % 13;
    const float* qr = qm + (size_t)(b * 13 + i) * CDIM;
    const float* kr = km + (size_t)(b * 13 + j) * CDIM;
    float s0 = 0.f, s1 = 0.f, s2 = 0.f, s3 = 0.f;
    for (int c = 0; c < CDIM; c += 4) {
      s0 = fmaf(qr[c + 0], kr[c + 0], s0);
      s1 = fmaf(qr[c + 1], kr[c + 1], s1);
      s2 = fmaf(qr[c + 2], kr[c + 2], s2);
      s3 = fmaf(qr[c + 3], kr[c + 3], s3);
    }
    att[i][j] = ((s0 + s1) + (s2 + s3)) * 0.03608439182435161f;  // 768^-0.5
  }
  __syncthreads();
  if (tid < 13) {
    float mx = -INFINITY;
    float e[13];
#pragma unroll
    for (int j = 0; j < 13; ++j) mx = fmaxf(mx, att[tid][j]);
    float sum = 0.f;
#pragma unroll
    for (int j = 0; j < 13; ++j) { e[j] = expf(att[tid][j] - mx); sum += e[j]; }
    float inv = 1.f / sum;
#pragma unroll
    for (int j = 0; j < 13; ++j) att[tid][j] = e[j] * inv;
  }
  __syncthreads();
  for (int i = tid; i < 13 * CDIM; i += 256) {
    int j = i / CDIM, d = i % CDIM;
    float s = 0.f;
#pragma unroll
    for (int kk = 0; kk < 13; ++kk) s = fmaf(att[j][kk], vm[(size_t)(b * 13 + kk) * CDIM + d], s);
    if (j == 0) {
      out[(size_t)b * NSEQ * CDIM + d] = s;
    } else {
      int t = vidx[(size_t)(b * TOPK + (j - 1)) * CDIM + d];
      out[((size_t)b * NSEQ + 1 + t) * CDIM + d] += s;
    }
  }
}

extern "C" void kernel_launch(void* const* d_in, const int* in_sizes, int n_in,
                              void* d_out, int out_size, void* d_ws, size_t ws_size,
                              hipStream_t stream) {
  const float* x = (const float*)d_in[0];
  const float* W = (const float*)d_in[1];
  const float* bias = (const float*)d_in[2];
  float* out = (float*)d_out;
  char* ws = (char*)d_ws;

  // R5-proven workspace layout: total 23,470,080 bytes
  float* cls = (float*)(ws + 0);               // 36864
  float* qm = (float*)(ws + 36864);            // 159744
  float* km = (float*)(ws + 196608);           // 159744
  float* vm = (float*)(ws + 356352);           // 159744
  int* vidx = (int*)(ws + 516096);             // 147456
  float* candQ = (float*)(ws + 663552);        // 4718592
  float* candK = (float*)(ws + 5382144);       // 4718592
  unsigned* candV = (unsigned*)(ws + 10100736);// 9437184
  int* cVi = (int*)(ws + 19537920);            // 393216
  __bf16* wh = (__bf16*)(ws + 19931136);       // 3538944 -> total 23470080

  hipLaunchKernelGGL(cls_kernel, dim3(36), dim3(256), 0, stream, x, W, bias, cls);
  hipLaunchKernelGGL(wconv_kernel, dim3(1728), dim3(256), 0, stream, W, wh);
  hipLaunchKernelGGL(fused_kernel, dim3(NDBLK, NCHUNK, BATCH), dim3(256), 0, stream,
                     x, wh, bias, cls, out, candQ, candK, candV);
  hipLaunchKernelGGL(vmerge_kernel, dim3(BATCH * CDIM / 64), dim3(256), 0, stream, candV, cVi);
  hipLaunchKernelGGL(merge_qk_kernel, dim3(BATCH * CDIM / 64), dim3(256), 0, stream,
                     cls, candQ, candK, qm, km, vm);
  hipLaunchKernelGGL(rescore_kernel, dim3(CDIM, BATCH), dim3(256), 0, stream,
                     x, W, bias, cls, cVi, vm, vidx);
  hipLaunchKernelGGL(attn_kernel, dim3(BATCH), dim3(256), 0, stream, qm, km, vm, vidx, out);
}